// Round 1
// baseline (3702.426 us; speedup 1.0000x reference)
//
#include <hip/hip_runtime.h>
#include <math.h>

#define CCH 128
#define HH 192
#define WW 192
#define BB 2
#define HW (HH*WW)        // 36864
#define CHW (CCH*HW)      // 4718592
#define BF 128            // B * f*f = 2*64
#define NN 576            // 24*24
#define SH 24

// ---------------- K1: per-batch sum / sumsq reduction ----------------
__global__ __launch_bounds__(256) void k_reduce(const float* __restrict__ x, float* __restrict__ stats) {
    int b = blockIdx.y;
    const float4* p = (const float4*)(x + (size_t)b*CHW) + (size_t)blockIdx.x*4096;
    float s = 0.f, sq = 0.f;
#pragma unroll
    for (int k = 0; k < 16; ++k) {
        float4 v = p[threadIdx.x + 256*k];
        s  += v.x + v.y + v.z + v.w;
        sq += v.x*v.x + v.y*v.y + v.z*v.z + v.w*v.w;
    }
    for (int off = 32; off; off >>= 1) { s += __shfl_down(s, off); sq += __shfl_down(sq, off); }
    __shared__ float ls[4], lq[4];
    int wave = threadIdx.x >> 6, lane = threadIdx.x & 63;
    if (lane == 0) { ls[wave] = s; lq[wave] = sq; }
    __syncthreads();
    if (threadIdx.x == 0) {
        atomicAdd(&stats[2*b],   ls[0]+ls[1]+ls[2]+ls[3]);
        atomicAdd(&stats[2*b+1], lq[0]+lq[1]+lq[2]+lq[3]);
    }
}

__global__ void k_finalize(float* stats) {
    int b = threadIdx.x;
    if (b < BB) {
        float s = stats[2*b], sq = stats[2*b+1];
        float mean = s / (float)CHW;
        float var = sq / (float)CHW - mean*mean;
        stats[4 + 2*b] = mean;
        stats[5 + 2*b] = rsqrtf(var + 1e-5f);
    }
}

// ---------------- K3: x -> V [Bf,N,C] (raw) and Xn [Bf,N,C] (normalized) ----------------
__global__ __launch_bounds__(256) void k_unshuffle(const float* __restrict__ x, const float* __restrict__ stats,
                                                   float* __restrict__ V, float* __restrict__ Xn) {
    __shared__ float t[128][65];
    int x0 = blockIdx.x * 64;
    int y  = blockIdx.y;
    int b  = blockIdx.z;
    float mean = stats[4+2*b], istd = stats[5+2*b];
    const float* src = x + (size_t)b*CHW + (size_t)y*WW + x0;
#pragma unroll
    for (int k = 0; k < 32; ++k) {
        int idx = threadIdx.x + 256*k;
        int c = idx >> 6, xl = idx & 63;
        t[c][xl] = src[(size_t)c*HW + xl];
    }
    __syncthreads();
    int i = y >> 3, dy = y & 7;
#pragma unroll
    for (int k = 0; k < 32; ++k) {
        int idx = threadIdx.x + 256*k;
        int c = idx & 127, xl = idx >> 7;
        int xx = x0 + xl;
        int j = xx >> 3, dx = xx & 7;
        int bf = (b << 6) + (dy << 3) + dx;
        int n = i*SH + j;
        size_t addr = ((size_t)bf*NN + n)*CCH + c;
        float v = t[c][xl];
        V[addr]  = v;
        Xn[addr] = (v - mean) * istd;
    }
}

// ---------------- K4: qkn = normalize_rows(Xn @ wqk) ----------------
__global__ __launch_bounds__(256) void k_qk(const float* __restrict__ Xn, const float* __restrict__ wqk,
                                            float* __restrict__ qkn) {
    __shared__ float Qs[64][129];
    __shared__ float ssb[64][4];
    int bid = blockIdx.x;           // 0..1151
    int bf = bid / 9, tile = bid % 9;
    int n0 = tile * 64;
    const float* src = Xn + ((size_t)bf*NN + n0)*CCH;
#pragma unroll
    for (int k = 0; k < 32; ++k) {
        int idx = threadIdx.x + 256*k;
        Qs[idx >> 7][idx & 127] = src[idx];
    }
    __syncthreads();
    int lane = threadIdx.x & 63;
    int wave = __builtin_amdgcn_readfirstlane(threadIdx.x >> 6);   // force SGPR -> s_load weights
    float acc[32];
#pragma unroll
    for (int k = 0; k < 32; ++k) acc[k] = 0.f;
    const float* wp = wqk + wave*32;
    for (int c = 0; c < 128; ++c) {
        float qv = Qs[lane][c];
#pragma unroll
        for (int k = 0; k < 32; ++k) acc[k] += qv * wp[c*128 + k];
    }
    float ss = 0.f;
#pragma unroll
    for (int k = 0; k < 32; ++k) ss += acc[k]*acc[k];
    ssb[lane][wave] = ss;
    __syncthreads();
    float tot = ssb[lane][0]+ssb[lane][1]+ssb[lane][2]+ssb[lane][3];
    float f = 1.f / (sqrtf(tot) + 1e-8f);
    float* dst = qkn + ((size_t)bf*NN + n0 + lane)*CCH + wave*32;
#pragma unroll
    for (int k = 0; k < 32; ++k) dst[k] = acc[k]*f;
}

// ---------------- K5: attention  O[bf,n,c] ----------------
// scores bounded in [0, 2/sqrt(128)] -> exp without max-subtraction is safe.
__global__ __launch_bounds__(256, 2) void k_attn(const float* __restrict__ qkn, const float* __restrict__ V,
                                                 float* __restrict__ O) {
    __shared__ float Qs[64][129];
    __shared__ float Ks[32][129];
    __shared__ float Vs[32][128];
    __shared__ float Ps[64][33];
    int tile = blockIdx.x, bf = blockIdx.y;
    int n0 = tile*64;
    int tid = threadIdx.x;
    int tx = tid & 15, ty = tid >> 4;
    const float* qsrc = qkn + ((size_t)bf*NN + n0)*CCH;
#pragma unroll
    for (int k = 0; k < 32; ++k) {
        int idx = tid + 256*k;
        Qs[idx >> 7][idx & 127] = qsrc[idx];
    }
    float o[4][8];
#pragma unroll
    for (int i = 0; i < 4; ++i)
#pragma unroll
        for (int k = 0; k < 8; ++k) o[i][k] = 0.f;
    float rsum[4] = {0.f, 0.f, 0.f, 0.f};
    const float scale = 0.08838834764831845f;   // 1/sqrt(128)
    for (int mt = 0; mt < 18; ++mt) {
        int m0 = mt*32;
        __syncthreads();   // covers initial Qs load + protects Ks/Vs/Ps from prior readers
        const float* ksrc = qkn + ((size_t)bf*NN + m0)*CCH;
        const float* vsrc = V   + ((size_t)bf*NN + m0)*CCH;
#pragma unroll
        for (int k = 0; k < 16; ++k) {
            int idx = tid + 256*k;
            int r = idx >> 7, c = idx & 127;
            Ks[r][c] = ksrc[idx];
            Vs[r][c] = vsrc[idx];
        }
        __syncthreads();
        // S = Q K^T  (thread: 4 rows x 2 cols)
        float s[4][2];
#pragma unroll
        for (int i = 0; i < 4; ++i) { s[i][0] = 0.f; s[i][1] = 0.f; }
        for (int c = 0; c < 128; ++c) {
            float qa[4], kb[2];
#pragma unroll
            for (int i = 0; i < 4; ++i) qa[i] = Qs[ty*4+i][c];
#pragma unroll
            for (int j = 0; j < 2; ++j) kb[j] = Ks[tx*2+j][c];
#pragma unroll
            for (int i = 0; i < 4; ++i)
#pragma unroll
                for (int j = 0; j < 2; ++j) s[i][j] += qa[i]*kb[j];
        }
        float rp[4];
#pragma unroll
        for (int i = 0; i < 4; ++i) {
            float p0 = __expf((s[i][0] + 1.f)*scale);
            float p1 = __expf((s[i][1] + 1.f)*scale);
            Ps[ty*4+i][tx*2]   = p0;
            Ps[ty*4+i][tx*2+1] = p1;
            rp[i] = p0 + p1;
        }
        // row-sum across the 16 tx lanes (low 4 lane bits)
#pragma unroll
        for (int off = 1; off < 16; off <<= 1) {
#pragma unroll
            for (int i = 0; i < 4; ++i) rp[i] += __shfl_xor(rp[i], off);
        }
#pragma unroll
        for (int i = 0; i < 4; ++i) rsum[i] += rp[i];
        __syncthreads();
        // O += P V  (thread: 4 rows x 8 cols)
        for (int mm = 0; mm < 32; ++mm) {
            float pa[4];
#pragma unroll
            for (int i = 0; i < 4; ++i) pa[i] = Ps[ty*4+i][mm];
            float vb[8];
#pragma unroll
            for (int k = 0; k < 8; ++k) vb[k] = Vs[mm][tx*8+k];
#pragma unroll
            for (int i = 0; i < 4; ++i)
#pragma unroll
                for (int k = 0; k < 8; ++k) o[i][k] += pa[i]*vb[k];
        }
    }
#pragma unroll
    for (int i = 0; i < 4; ++i) {
        float inv = 1.f / rsum[i];
        float* dst = O + ((size_t)bf*NN + n0 + ty*4 + i)*CCH + tx*8;
#pragma unroll
        for (int k = 0; k < 8; ++k) dst[k] = o[i][k]*inv;
    }
}

// ---------------- K6: y[B,C,H,W] = x + shuffle(O) ----------------
__global__ __launch_bounds__(256) void k_shuffle_add(const float* __restrict__ O, const float* __restrict__ x,
                                                     float* __restrict__ y) {
    __shared__ float t[128][65];
    int x0 = blockIdx.x * 64;
    int yy = blockIdx.y;
    int b  = blockIdx.z;
    int i = yy >> 3, dy = yy & 7;
#pragma unroll
    for (int k = 0; k < 32; ++k) {
        int idx = threadIdx.x + 256*k;
        int c = idx & 127, xl = idx >> 7;
        int xx = x0 + xl;
        int j = xx >> 3, dx = xx & 7;
        int bf = (b << 6) + (dy << 3) + dx;
        int n = i*SH + j;
        t[c][xl] = O[((size_t)bf*NN + n)*CCH + c];
    }
    __syncthreads();
    size_t base = (size_t)b*CHW + (size_t)yy*WW + x0;
#pragma unroll
    for (int k = 0; k < 32; ++k) {
        int idx = threadIdx.x + 256*k;
        int c = idx >> 6, xl = idx & 63;
        size_t a = base + (size_t)c*HW + xl;
        y[a] = x[a] + t[c][xl];
    }
}

// ---------------- K7/K8: 3x3 dilated (d=2, pad=2) conv + bias + optional relu ----------------
// block: (4 co) x (64x64 spatial tile); thread: 4x4 outputs on a stride-2 lattice
__global__ __launch_bounds__(256, 2) void k_conv3(const float* __restrict__ in, const float* __restrict__ w,
                                                  const float* __restrict__ bias, float* __restrict__ out,
                                                  int relu) {
    __shared__ float t[68][69];
    int cog  = blockIdx.x;             // 0..31
    int tile = blockIdx.y;             // 0..8
    int b    = blockIdx.z;
    int x0 = (tile % 3)*64, y0 = (tile / 3)*64;
    int cobase = cog*4;
    int tid = threadIdx.x;
    int tx = tid & 15, ty = tid >> 4;
    int rx = ((tx >> 1) << 3) + (tx & 1);
    int ry = ((ty >> 1) << 3) + (ty & 1);
    float acc[4][4][4];
#pragma unroll
    for (int cl = 0; cl < 4; ++cl)
#pragma unroll
        for (int a = 0; a < 4; ++a)
#pragma unroll
            for (int bb = 0; bb < 4; ++bb) acc[cl][a][bb] = 0.f;

    for (int ci = 0; ci < 128; ++ci) {
        __syncthreads();
        const float* src = in + ((size_t)b*128 + ci)*HW;
        for (int k = 0; k < 19; ++k) {
            int idx = tid + 256*k;
            if (idx < 68*68) {
                int r = idx / 68, cc = idx % 68;
                int gy = y0 - 2 + r, gx = x0 - 2 + cc;
                float v = 0.f;
                if (gy >= 0 && gy < HH && gx >= 0 && gx < WW) v = src[gy*WW + gx];
                t[r][cc] = v;
            }
        }
        __syncthreads();
        float inv[6][6];
#pragma unroll
        for (int a = 0; a < 6; ++a)
#pragma unroll
            for (int bb = 0; bb < 6; ++bb) inv[a][bb] = t[ry + 2*a][rx + 2*bb];
        const float* wp = w + ((size_t)cobase*128 + ci)*9;
#pragma unroll
        for (int cl = 0; cl < 4; ++cl) {
#pragma unroll
            for (int ky = 0; ky < 3; ++ky)
#pragma unroll
                for (int kx = 0; kx < 3; ++kx) {
                    float wv = wp[(size_t)cl*128*9 + ky*3 + kx];
#pragma unroll
                    for (int a = 0; a < 4; ++a)
#pragma unroll
                        for (int bb = 0; bb < 4; ++bb)
                            acc[cl][a][bb] += wv * inv[a+ky][bb+kx];
                }
        }
    }
#pragma unroll
    for (int cl = 0; cl < 4; ++cl) {
        float bv = bias[cobase+cl];
        float* dst = out + ((size_t)b*128 + cobase + cl)*HW;
#pragma unroll
        for (int a = 0; a < 4; ++a)
#pragma unroll
            for (int bb = 0; bb < 4; ++bb) {
                int gy = y0 + ry + 2*a, gx = x0 + rx + 2*bb;
                float v = acc[cl][a][bb] + bv;
                if (relu) v = fmaxf(v, 0.f);
                dst[gy*WW + gx] = v;
            }
    }
}

// ---------------- K9: out = x + (w3 @ h) + b3  (1x1 conv) ----------------
__global__ __launch_bounds__(256) void k_conv1x1(const float* __restrict__ h, const float* __restrict__ w3,
                                                 const float* __restrict__ b3, const float* __restrict__ x,
                                                 float* __restrict__ out) {
    __shared__ float t[128][64];
    int pix0 = blockIdx.x * 64;
    int b = blockIdx.y;
    int tid = threadIdx.x;
#pragma unroll
    for (int k = 0; k < 32; ++k) {
        int idx = tid + 256*k;
        int ci = idx >> 6, p = idx & 63;
        t[ci][p] = h[((size_t)b*128 + ci)*HW + pix0 + p];
    }
    __syncthreads();
    int lane = tid & 63;
    int wave = __builtin_amdgcn_readfirstlane(tid >> 6);
    float acc[32];
#pragma unroll
    for (int k = 0; k < 32; ++k) acc[k] = 0.f;
    const float* wp = w3 + (size_t)wave*32*128;
    for (int ci = 0; ci < 128; ++ci) {
        float v = t[ci][lane];
#pragma unroll
        for (int k = 0; k < 32; ++k) acc[k] += wp[k*128 + ci] * v;
    }
#pragma unroll
    for (int k = 0; k < 32; ++k) {
        int co = wave*32 + k;
        size_t a = ((size_t)b*128 + co)*HW + pix0 + lane;
        out[a] = x[a] + acc[k] + b3[co];
    }
}

extern "C" void kernel_launch(void* const* d_in, const int* in_sizes, int n_in,
                              void* d_out, int out_size, void* d_ws, size_t ws_size,
                              hipStream_t stream) {
    (void)in_sizes; (void)n_in; (void)out_size; (void)ws_size;
    const float* x   = (const float*)d_in[0];
    const float* wqk = (const float*)d_in[1];
    const float* w1  = (const float*)d_in[2];
    const float* b1  = (const float*)d_in[3];
    const float* w2  = (const float*)d_in[4];
    const float* b2  = (const float*)d_in[5];
    const float* w3  = (const float*)d_in[6];
    const float* b3  = (const float*)d_in[7];
    float* out = (float*)d_out;
    char* ws = (char*)d_ws;
    float* stats = (float*)ws;
    const size_t SZ = (size_t)BF * NN * CCH * sizeof(float);   // 37,748,736 B
    float* A  = (float*)(ws + 256);
    float* Bb = (float*)(ws + 256 + SZ);
    float* Cc = (float*)(ws + 256 + 2*SZ);

    hipMemsetAsync(stats, 0, 4*sizeof(float), stream);
    k_reduce     <<<dim3(288, 2),     256, 0, stream>>>(x, stats);
    k_finalize   <<<1, 64,            0, stream>>>(stats);
    k_unshuffle  <<<dim3(3, 192, 2),  256, 0, stream>>>(x, stats, A, Bb);     // V->A, Xn->Bb
    k_qk         <<<1152,             256, 0, stream>>>(Bb, wqk, Cc);         // qkn->Cc
    k_attn       <<<dim3(9, 128),     256, 0, stream>>>(Cc, A, Bb);           // O->Bb
    k_shuffle_add<<<dim3(3, 192, 2),  256, 0, stream>>>(Bb, x, A);            // y = x+attn -> A
    k_conv3      <<<dim3(32, 9, 2),   256, 0, stream>>>(A, w1, b1, Cc, 1);    // h1->Cc
    k_conv3      <<<dim3(32, 9, 2),   256, 0, stream>>>(Cc, w2, b2, Bb, 1);   // h2->Bb
    k_conv1x1    <<<dim3(576, 2),     256, 0, stream>>>(Bb, w3, b3, x, out);  // out = x + conv1x1
}

// Round 2
// 2740.343 us; speedup vs baseline: 1.3511x; 1.3511x over previous
//
#include <hip/hip_runtime.h>
#include <math.h>

#define CCH 128
#define HH 192
#define WW 192
#define BB 2
#define HW (HH*WW)        // 36864
#define CHW (CCH*HW)      // 4718592
#define BF 128            // B * f*f = 2*64
#define NN 576            // 24*24
#define SH 24

// ---------------- K1: per-batch sum / sumsq reduction ----------------
__global__ __launch_bounds__(256) void k_reduce(const float* __restrict__ x, float* __restrict__ stats) {
    int b = blockIdx.y;
    const float4* p = (const float4*)(x + (size_t)b*CHW) + (size_t)blockIdx.x*4096;
    float s = 0.f, sq = 0.f;
#pragma unroll
    for (int k = 0; k < 16; ++k) {
        float4 v = p[threadIdx.x + 256*k];
        s  += v.x + v.y + v.z + v.w;
        sq += v.x*v.x + v.y*v.y + v.z*v.z + v.w*v.w;
    }
    for (int off = 32; off; off >>= 1) { s += __shfl_down(s, off); sq += __shfl_down(sq, off); }
    __shared__ float ls[4], lq[4];
    int wave = threadIdx.x >> 6, lane = threadIdx.x & 63;
    if (lane == 0) { ls[wave] = s; lq[wave] = sq; }
    __syncthreads();
    if (threadIdx.x == 0) {
        atomicAdd(&stats[2*b],   ls[0]+ls[1]+ls[2]+ls[3]);
        atomicAdd(&stats[2*b+1], lq[0]+lq[1]+lq[2]+lq[3]);
    }
}

__global__ void k_finalize(float* stats) {
    int b = threadIdx.x;
    if (b < BB) {
        float s = stats[2*b], sq = stats[2*b+1];
        float mean = s / (float)CHW;
        float var = sq / (float)CHW - mean*mean;
        stats[4 + 2*b] = mean;
        stats[5 + 2*b] = rsqrtf(var + 1e-5f);
    }
}

// ---------------- K3: x -> V [Bf,N,C] (raw) and Xn [Bf,N,C] (normalized) ----------------
__global__ __launch_bounds__(256) void k_unshuffle(const float* __restrict__ x, const float* __restrict__ stats,
                                                   float* __restrict__ V, float* __restrict__ Xn) {
    __shared__ float t[128][65];
    int x0 = blockIdx.x * 64;
    int y  = blockIdx.y;
    int b  = blockIdx.z;
    float mean = stats[4+2*b], istd = stats[5+2*b];
    const float* src = x + (size_t)b*CHW + (size_t)y*WW + x0;
#pragma unroll
    for (int k = 0; k < 32; ++k) {
        int idx = threadIdx.x + 256*k;
        int c = idx >> 6, xl = idx & 63;
        t[c][xl] = src[(size_t)c*HW + xl];
    }
    __syncthreads();
    int i = y >> 3, dy = y & 7;
#pragma unroll
    for (int k = 0; k < 32; ++k) {
        int idx = threadIdx.x + 256*k;
        int c = idx & 127, xl = idx >> 7;
        int xx = x0 + xl;
        int j = xx >> 3, dx = xx & 7;
        int bf = (b << 6) + (dy << 3) + dx;
        int n = i*SH + j;
        size_t addr = ((size_t)bf*NN + n)*CCH + c;
        float v = t[c][xl];
        V[addr]  = v;
        Xn[addr] = (v - mean) * istd;
    }
}

// ---------------- K4: qkn = normalize_rows(Xn @ wqk) ----------------
__global__ __launch_bounds__(256) void k_qk(const float* __restrict__ Xn, const float* __restrict__ wqk,
                                            float* __restrict__ qkn) {
    __shared__ float Qs[64][129];
    __shared__ float ssb[64][4];
    int bid = blockIdx.x;           // 0..1151
    int bf = bid / 9, tile = bid % 9;
    int n0 = tile * 64;
    const float* src = Xn + ((size_t)bf*NN + n0)*CCH;
#pragma unroll
    for (int k = 0; k < 32; ++k) {
        int idx = threadIdx.x + 256*k;
        Qs[idx >> 7][idx & 127] = src[idx];
    }
    __syncthreads();
    int lane = threadIdx.x & 63;
    int wave = __builtin_amdgcn_readfirstlane(threadIdx.x >> 6);
    float acc[32];
#pragma unroll
    for (int k = 0; k < 32; ++k) acc[k] = 0.f;
    const float* wp = wqk + wave*32;
    for (int c = 0; c < 128; ++c) {
        float qv = Qs[lane][c];
#pragma unroll
        for (int k = 0; k < 32; ++k) acc[k] += qv * wp[c*128 + k];
    }
    float ss = 0.f;
#pragma unroll
    for (int k = 0; k < 32; ++k) ss += acc[k]*acc[k];
    ssb[lane][wave] = ss;
    __syncthreads();
    float tot = ssb[lane][0]+ssb[lane][1]+ssb[lane][2]+ssb[lane][3];
    float f = 1.f / (sqrtf(tot) + 1e-8f);
    float* dst = qkn + ((size_t)bf*NN + n0 + lane)*CCH + wave*32;
#pragma unroll
    for (int k = 0; k < 32; ++k) dst[k] = acc[k]*f;
}

// ---------------- K5: attention  O[bf,n,c] ----------------
__global__ __launch_bounds__(256, 2) void k_attn(const float* __restrict__ qkn, const float* __restrict__ V,
                                                 float* __restrict__ O) {
    __shared__ float Qs[64][129];
    __shared__ float Ks[32][129];
    __shared__ float Vs[32][128];
    __shared__ float Ps[64][33];
    int tile = blockIdx.x, bf = blockIdx.y;
    int n0 = tile*64;
    int tid = threadIdx.x;
    int tx = tid & 15, ty = tid >> 4;
    const float* qsrc = qkn + ((size_t)bf*NN + n0)*CCH;
#pragma unroll
    for (int k = 0; k < 32; ++k) {
        int idx = tid + 256*k;
        Qs[idx >> 7][idx & 127] = qsrc[idx];
    }
    float o[4][8];
#pragma unroll
    for (int i = 0; i < 4; ++i)
#pragma unroll
        for (int k = 0; k < 8; ++k) o[i][k] = 0.f;
    float rsum[4] = {0.f, 0.f, 0.f, 0.f};
    const float scale = 0.08838834764831845f;   // 1/sqrt(128)
    for (int mt = 0; mt < 18; ++mt) {
        int m0 = mt*32;
        __syncthreads();
        const float* ksrc = qkn + ((size_t)bf*NN + m0)*CCH;
        const float* vsrc = V   + ((size_t)bf*NN + m0)*CCH;
#pragma unroll
        for (int k = 0; k < 16; ++k) {
            int idx = tid + 256*k;
            int r = idx >> 7, c = idx & 127;
            Ks[r][c] = ksrc[idx];
            Vs[r][c] = vsrc[idx];
        }
        __syncthreads();
        float s[4][2];
#pragma unroll
        for (int i = 0; i < 4; ++i) { s[i][0] = 0.f; s[i][1] = 0.f; }
        for (int c = 0; c < 128; ++c) {
            float qa[4], kb[2];
#pragma unroll
            for (int i = 0; i < 4; ++i) qa[i] = Qs[ty*4+i][c];
#pragma unroll
            for (int j = 0; j < 2; ++j) kb[j] = Ks[tx*2+j][c];
#pragma unroll
            for (int i = 0; i < 4; ++i)
#pragma unroll
                for (int j = 0; j < 2; ++j) s[i][j] += qa[i]*kb[j];
        }
        float rp[4];
#pragma unroll
        for (int i = 0; i < 4; ++i) {
            float p0 = __expf((s[i][0] + 1.f)*scale);
            float p1 = __expf((s[i][1] + 1.f)*scale);
            Ps[ty*4+i][tx*2]   = p0;
            Ps[ty*4+i][tx*2+1] = p1;
            rp[i] = p0 + p1;
        }
#pragma unroll
        for (int off = 1; off < 16; off <<= 1) {
#pragma unroll
            for (int i = 0; i < 4; ++i) rp[i] += __shfl_xor(rp[i], off);
        }
#pragma unroll
        for (int i = 0; i < 4; ++i) rsum[i] += rp[i];
        __syncthreads();
        for (int mm = 0; mm < 32; ++mm) {
            float pa[4];
#pragma unroll
            for (int i = 0; i < 4; ++i) pa[i] = Ps[ty*4+i][mm];
            float vb[8];
#pragma unroll
            for (int k = 0; k < 8; ++k) vb[k] = Vs[mm][tx*8+k];
#pragma unroll
            for (int i = 0; i < 4; ++i)
#pragma unroll
                for (int k = 0; k < 8; ++k) o[i][k] += pa[i]*vb[k];
        }
    }
#pragma unroll
    for (int i = 0; i < 4; ++i) {
        float inv = 1.f / rsum[i];
        float* dst = O + ((size_t)bf*NN + n0 + ty*4 + i)*CCH + tx*8;
#pragma unroll
        for (int k = 0; k < 8; ++k) dst[k] = o[i][k]*inv;
    }
}

// ---------------- K6: y[B,C,H,W] = x + shuffle(O) ----------------
__global__ __launch_bounds__(256) void k_shuffle_add(const float* __restrict__ O, const float* __restrict__ x,
                                                     float* __restrict__ y) {
    __shared__ float t[128][65];
    int x0 = blockIdx.x * 64;
    int yy = blockIdx.y;
    int b  = blockIdx.z;
    int i = yy >> 3, dy = yy & 7;
#pragma unroll
    for (int k = 0; k < 32; ++k) {
        int idx = threadIdx.x + 256*k;
        int c = idx & 127, xl = idx >> 7;
        int xx = x0 + xl;
        int j = xx >> 3, dx = xx & 7;
        int bf = (b << 6) + (dy << 3) + dx;
        int n = i*SH + j;
        t[c][xl] = O[((size_t)bf*NN + n)*CCH + c];
    }
    __syncthreads();
    size_t base = (size_t)b*CHW + (size_t)yy*WW + x0;
#pragma unroll
    for (int k = 0; k < 32; ++k) {
        int idx = threadIdx.x + 256*k;
        int c = idx >> 6, xl = idx & 63;
        size_t a = base + (size_t)c*HW + xl;
        y[a] = x[a] + t[c][xl];
    }
}

// ---------------- K7/K8: 3x3 dilated (d=2, pad=2) conv, parity-decomposed over y ----------------
// Output-row parity fixed per block => dilated taps hit plane rows i-1,i,i+1 (image rows stride 2),
// x stays contiguous. Block: 16 co x (16 plane rows x 64 cols). ci-chunked by 8 (16 barriers total).
// Thread: 8 co x 1 row x 8 contiguous cols, fully register-blocked; float4 LDS reads, broadcast weights.
__global__ __launch_bounds__(256, 3) void k_conv3(const float* __restrict__ in, const float* __restrict__ w,
                                                  const float* __restrict__ bias, float* __restrict__ out,
                                                  int relu) {
    __shared__ float t[8][18][76];     // [ci_local][plane row + halo][col + halo, padded]
    __shared__ float wsm[8][9][16];    // [ci_local][tap][co within cog]
    int cog  = blockIdx.x;             // 0..7  -> co base 16*cog
    int tile = blockIdx.y;             // 0..35 : py*18 + yt*3 + xt
    int b    = blockIdx.z;
    int py = tile / 18;
    int r3 = tile % 18;
    int yt = r3 / 3, xt = r3 % 3;
    int i0 = yt * 16;                  // plane-row base (plane = rows of parity py, 96 rows)
    int x0 = xt * 64;
    int tid = threadIdx.x;
    int cs  = tid >> 7;                // 0..1 -> co sub-base 8*cs
    int sid = tid & 127;
    int sy  = sid >> 3;                // 0..15 plane row within tile
    int sx  = sid & 7;                 // 0..7  col-octet within tile
    int cobase = cog*16 + cs*8;

    float acc[8][8];
#pragma unroll
    for (int k = 0; k < 8; ++k)
#pragma unroll
        for (int bb = 0; bb < 8; ++bb) acc[k][bb] = 0.f;

    const float* inb = in + (size_t)b*CHW;
    for (int chunk = 0; chunk < 16; ++chunk) {
        __syncthreads();
        // stage input: 8 ci x 18 plane rows x 68 cols (zero-padded at edges)
        for (int k = 0; k < 39; ++k) {
            int idx = tid + 256*k;
            if (idx < 8*18*68) {
                int ci_l = idx / 1224;
                int rr = idx - ci_l*1224;
                int r = rr / 68;
                int c = rr - r*68;
                int p = i0 - 1 + r;            // plane row
                int xx = x0 - 2 + c;           // image col
                float v = 0.f;
                if (p >= 0 && p < 96 && xx >= 0 && xx < WW)
                    v = inb[(size_t)(chunk*8 + ci_l)*HW + (size_t)(2*p + py)*WW + xx];
                t[ci_l][r][c] = v;
            }
        }
        // stage weights: 8 ci x 9 taps x 16 co
        for (int k = 0; k < 5; ++k) {
            int idx = tid + 256*k;
            if (idx < 1152) {
                int ci_l = idx / 144;
                int rr = idx - ci_l*144;
                int tap = rr >> 4;
                int col = rr & 15;
                wsm[ci_l][tap][col] = w[((size_t)(cog*16 + col)*128 + chunk*8 + ci_l)*9 + tap];
            }
        }
        __syncthreads();
#pragma unroll
        for (int ci = 0; ci < 8; ++ci) {
            float inr[3][12];
#pragma unroll
            for (int a = 0; a < 3; ++a)
#pragma unroll
                for (int c4 = 0; c4 < 3; ++c4)
                    *(float4*)&inr[a][4*c4] = *(const float4*)&t[ci][sy + a][8*sx + 4*c4];
#pragma unroll
            for (int ky = 0; ky < 3; ++ky)
#pragma unroll
                for (int kx = 0; kx < 3; ++kx) {
                    float wv[8];
                    *(float4*)&wv[0] = *(const float4*)&wsm[ci][ky*3+kx][cs*8];
                    *(float4*)&wv[4] = *(const float4*)&wsm[ci][ky*3+kx][cs*8+4];
#pragma unroll
                    for (int k = 0; k < 8; ++k)
#pragma unroll
                        for (int bb = 0; bb < 8; ++bb)
                            acc[k][bb] += wv[k] * inr[ky][bb + 2*kx];
                }
        }
    }
    int yrow = 2*(i0 + sy) + py;
#pragma unroll
    for (int k = 0; k < 8; ++k) {
        int co = cobase + k;
        float bv = bias[co];
        float* dst = out + ((size_t)b*128 + co)*HW + (size_t)yrow*WW + x0 + 8*sx;
        float4 v0, v1;
        v0.x = acc[k][0]+bv; v0.y = acc[k][1]+bv; v0.z = acc[k][2]+bv; v0.w = acc[k][3]+bv;
        v1.x = acc[k][4]+bv; v1.y = acc[k][5]+bv; v1.z = acc[k][6]+bv; v1.w = acc[k][7]+bv;
        if (relu) {
            v0.x = fmaxf(v0.x, 0.f); v0.y = fmaxf(v0.y, 0.f); v0.z = fmaxf(v0.z, 0.f); v0.w = fmaxf(v0.w, 0.f);
            v1.x = fmaxf(v1.x, 0.f); v1.y = fmaxf(v1.y, 0.f); v1.z = fmaxf(v1.z, 0.f); v1.w = fmaxf(v1.w, 0.f);
        }
        *(float4*)&dst[0] = v0;
        *(float4*)&dst[4] = v1;
    }
}

// ---------------- K9: out = x + (w3 @ h) + b3  (1x1 conv) ----------------
__global__ __launch_bounds__(256) void k_conv1x1(const float* __restrict__ h, const float* __restrict__ w3,
                                                 const float* __restrict__ b3, const float* __restrict__ x,
                                                 float* __restrict__ out) {
    __shared__ float t[128][64];
    int pix0 = blockIdx.x * 64;
    int b = blockIdx.y;
    int tid = threadIdx.x;
#pragma unroll
    for (int k = 0; k < 32; ++k) {
        int idx = tid + 256*k;
        int ci = idx >> 6, p = idx & 63;
        t[ci][p] = h[((size_t)b*128 + ci)*HW + pix0 + p];
    }
    __syncthreads();
    int lane = tid & 63;
    int wave = __builtin_amdgcn_readfirstlane(tid >> 6);
    float acc[32];
#pragma unroll
    for (int k = 0; k < 32; ++k) acc[k] = 0.f;
    const float* wp = w3 + (size_t)wave*32*128;
    for (int ci = 0; ci < 128; ++ci) {
        float v = t[ci][lane];
#pragma unroll
        for (int k = 0; k < 32; ++k) acc[k] += wp[k*128 + ci] * v;
    }
#pragma unroll
    for (int k = 0; k < 32; ++k) {
        int co = wave*32 + k;
        size_t a = ((size_t)b*128 + co)*HW + pix0 + lane;
        out[a] = x[a] + acc[k] + b3[co];
    }
}

extern "C" void kernel_launch(void* const* d_in, const int* in_sizes, int n_in,
                              void* d_out, int out_size, void* d_ws, size_t ws_size,
                              hipStream_t stream) {
    (void)in_sizes; (void)n_in; (void)out_size; (void)ws_size;
    const float* x   = (const float*)d_in[0];
    const float* wqk = (const float*)d_in[1];
    const float* w1  = (const float*)d_in[2];
    const float* b1  = (const float*)d_in[3];
    const float* w2  = (const float*)d_in[4];
    const float* b2  = (const float*)d_in[5];
    const float* w3  = (const float*)d_in[6];
    const float* b3  = (const float*)d_in[7];
    float* out = (float*)d_out;
    char* ws = (char*)d_ws;
    float* stats = (float*)ws;
    const size_t SZ = (size_t)BF * NN * CCH * sizeof(float);   // 37,748,736 B
    float* A  = (float*)(ws + 256);
    float* Bb = (float*)(ws + 256 + SZ);
    float* Cc = (float*)(ws + 256 + 2*SZ);

    hipMemsetAsync(stats, 0, 4*sizeof(float), stream);
    k_reduce     <<<dim3(288, 2),     256, 0, stream>>>(x, stats);
    k_finalize   <<<1, 64,            0, stream>>>(stats);
    k_unshuffle  <<<dim3(3, 192, 2),  256, 0, stream>>>(x, stats, A, Bb);     // V->A, Xn->Bb
    k_qk         <<<1152,             256, 0, stream>>>(Bb, wqk, Cc);         // qkn->Cc
    k_attn       <<<dim3(9, 128),     256, 0, stream>>>(Cc, A, Bb);           // O->Bb
    k_shuffle_add<<<dim3(3, 192, 2),  256, 0, stream>>>(Bb, x, A);            // y = x+attn -> A
    k_conv3      <<<dim3(8, 36, 2),   256, 0, stream>>>(A, w1, b1, Cc, 1);    // h1->Cc
    k_conv3      <<<dim3(8, 36, 2),   256, 0, stream>>>(Cc, w2, b2, Bb, 1);   // h2->Bb
    k_conv1x1    <<<dim3(576, 2),     256, 0, stream>>>(Bb, w3, b3, x, out);  // out = x + conv1x1
}

// Round 3
// 839.542 us; speedup vs baseline: 4.4101x; 3.2641x over previous
//
#include <hip/hip_runtime.h>
#include <math.h>

#define CCH 128
#define HH 192
#define WW 192
#define BB 2
#define HW (HH*WW)        // 36864
#define CHW (CCH*HW)      // 4718592
#define BF 128            // B * f*f = 2*64
#define NN 576            // 24*24
#define SH 24

typedef __attribute__((ext_vector_type(8))) short short8;
typedef __attribute__((ext_vector_type(4))) float floatx4;
typedef unsigned int uint32;
typedef unsigned short ushort16;

__device__ __forceinline__ unsigned short bf16r(float f) {
    uint32 u = __float_as_uint(f);
    u += 0x7fffu + ((u >> 16) & 1u);
    return (unsigned short)(u >> 16);
}

// ---------------- K1: per-batch sum / sumsq reduction ----------------
__global__ __launch_bounds__(256) void k_reduce(const float* __restrict__ x, float* __restrict__ stats) {
    int b = blockIdx.y;
    const float4* p = (const float4*)(x + (size_t)b*CHW) + (size_t)blockIdx.x*4096;
    float s = 0.f, sq = 0.f;
#pragma unroll
    for (int k = 0; k < 16; ++k) {
        float4 v = p[threadIdx.x + 256*k];
        s  += v.x + v.y + v.z + v.w;
        sq += v.x*v.x + v.y*v.y + v.z*v.z + v.w*v.w;
    }
    for (int off = 32; off; off >>= 1) { s += __shfl_down(s, off); sq += __shfl_down(sq, off); }
    __shared__ float ls[4], lq[4];
    int wave = threadIdx.x >> 6, lane = threadIdx.x & 63;
    if (lane == 0) { ls[wave] = s; lq[wave] = sq; }
    __syncthreads();
    if (threadIdx.x == 0) {
        atomicAdd(&stats[2*b],   ls[0]+ls[1]+ls[2]+ls[3]);
        atomicAdd(&stats[2*b+1], lq[0]+lq[1]+lq[2]+lq[3]);
    }
}

__global__ void k_finalize(float* stats) {
    int b = threadIdx.x;
    if (b < BB) {
        float s = stats[2*b], sq = stats[2*b+1];
        float mean = s / (float)CHW;
        float var = sq / (float)CHW - mean*mean;
        stats[4 + 2*b] = mean;
        stats[5 + 2*b] = rsqrtf(var + 1e-5f);
    }
}

// ---------------- K3: x -> V [Bf,N,C] (raw) and Xn [Bf,N,C] (normalized) ----------------
__global__ __launch_bounds__(256) void k_unshuffle(const float* __restrict__ x, const float* __restrict__ stats,
                                                   float* __restrict__ V, float* __restrict__ Xn) {
    __shared__ float t[128][65];
    int x0 = blockIdx.x * 64;
    int y  = blockIdx.y;
    int b  = blockIdx.z;
    float mean = stats[4+2*b], istd = stats[5+2*b];
    const float* src = x + (size_t)b*CHW + (size_t)y*WW + x0;
#pragma unroll
    for (int k = 0; k < 32; ++k) {
        int idx = threadIdx.x + 256*k;
        int c = idx >> 6, xl = idx & 63;
        t[c][xl] = src[(size_t)c*HW + xl];
    }
    __syncthreads();
    int i = y >> 3, dy = y & 7;
#pragma unroll
    for (int k = 0; k < 32; ++k) {
        int idx = threadIdx.x + 256*k;
        int c = idx & 127, xl = idx >> 7;
        int xx = x0 + xl;
        int j = xx >> 3, dx = xx & 7;
        int bf = (b << 6) + (dy << 3) + dx;
        int n = i*SH + j;
        size_t addr = ((size_t)bf*NN + n)*CCH + c;
        float v = t[c][xl];
        V[addr]  = v;
        Xn[addr] = (v - mean) * istd;
    }
}

// ---------------- K4: qkn = normalize_rows(Xn @ wqk) ----------------
__global__ __launch_bounds__(256) void k_qk(const float* __restrict__ Xn, const float* __restrict__ wqk,
                                            float* __restrict__ qkn) {
    __shared__ float Qs[64][129];
    __shared__ float ssb[64][4];
    int bid = blockIdx.x;           // 0..1151
    int bf = bid / 9, tile = bid % 9;
    int n0 = tile * 64;
    const float* src = Xn + ((size_t)bf*NN + n0)*CCH;
#pragma unroll
    for (int k = 0; k < 32; ++k) {
        int idx = threadIdx.x + 256*k;
        Qs[idx >> 7][idx & 127] = src[idx];
    }
    __syncthreads();
    int lane = threadIdx.x & 63;
    int wave = __builtin_amdgcn_readfirstlane(threadIdx.x >> 6);
    float acc[32];
#pragma unroll
    for (int k = 0; k < 32; ++k) acc[k] = 0.f;
    const float* wp = wqk + wave*32;
    for (int c = 0; c < 128; ++c) {
        float qv = Qs[lane][c];
#pragma unroll
        for (int k = 0; k < 32; ++k) acc[k] += qv * wp[c*128 + k];
    }
    float ss = 0.f;
#pragma unroll
    for (int k = 0; k < 32; ++k) ss += acc[k]*acc[k];
    ssb[lane][wave] = ss;
    __syncthreads();
    float tot = ssb[lane][0]+ssb[lane][1]+ssb[lane][2]+ssb[lane][3];
    float f = 1.f / (sqrtf(tot) + 1e-8f);
    float* dst = qkn + ((size_t)bf*NN + n0 + lane)*CCH + wave*32;
#pragma unroll
    for (int k = 0; k < 32; ++k) dst[k] = acc[k]*f;
}

// ---------------- K5: attention  O[bf,n,c] ----------------
__global__ __launch_bounds__(256, 2) void k_attn(const float* __restrict__ qkn, const float* __restrict__ V,
                                                 float* __restrict__ O) {
    __shared__ float Qs[64][129];
    __shared__ float Ks[32][129];
    __shared__ float Vs[32][128];
    __shared__ float Ps[64][33];
    int tile = blockIdx.x, bf = blockIdx.y;
    int n0 = tile*64;
    int tid = threadIdx.x;
    int tx = tid & 15, ty = tid >> 4;
    const float* qsrc = qkn + ((size_t)bf*NN + n0)*CCH;
#pragma unroll
    for (int k = 0; k < 32; ++k) {
        int idx = tid + 256*k;
        Qs[idx >> 7][idx & 127] = qsrc[idx];
    }
    float o[4][8];
#pragma unroll
    for (int i = 0; i < 4; ++i)
#pragma unroll
        for (int k = 0; k < 8; ++k) o[i][k] = 0.f;
    float rsum[4] = {0.f, 0.f, 0.f, 0.f};
    const float scale = 0.08838834764831845f;   // 1/sqrt(128)
    for (int mt = 0; mt < 18; ++mt) {
        int m0 = mt*32;
        __syncthreads();
        const float* ksrc = qkn + ((size_t)bf*NN + m0)*CCH;
        const float* vsrc = V   + ((size_t)bf*NN + m0)*CCH;
#pragma unroll
        for (int k = 0; k < 16; ++k) {
            int idx = tid + 256*k;
            int r = idx >> 7, c = idx & 127;
            Ks[r][c] = ksrc[idx];
            Vs[r][c] = vsrc[idx];
        }
        __syncthreads();
        float s[4][2];
#pragma unroll
        for (int i = 0; i < 4; ++i) { s[i][0] = 0.f; s[i][1] = 0.f; }
        for (int c = 0; c < 128; ++c) {
            float qa[4], kb[2];
#pragma unroll
            for (int i = 0; i < 4; ++i) qa[i] = Qs[ty*4+i][c];
#pragma unroll
            for (int j = 0; j < 2; ++j) kb[j] = Ks[tx*2+j][c];
#pragma unroll
            for (int i = 0; i < 4; ++i)
#pragma unroll
                for (int j = 0; j < 2; ++j) s[i][j] += qa[i]*kb[j];
        }
        float rp[4];
#pragma unroll
        for (int i = 0; i < 4; ++i) {
            float p0 = __expf((s[i][0] + 1.f)*scale);
            float p1 = __expf((s[i][1] + 1.f)*scale);
            Ps[ty*4+i][tx*2]   = p0;
            Ps[ty*4+i][tx*2+1] = p1;
            rp[i] = p0 + p1;
        }
#pragma unroll
        for (int off = 1; off < 16; off <<= 1) {
#pragma unroll
            for (int i = 0; i < 4; ++i) rp[i] += __shfl_xor(rp[i], off);
        }
#pragma unroll
        for (int i = 0; i < 4; ++i) rsum[i] += rp[i];
        __syncthreads();
        for (int mm = 0; mm < 32; ++mm) {
            float pa[4];
#pragma unroll
            for (int i = 0; i < 4; ++i) pa[i] = Ps[ty*4+i][mm];
            float vb[8];
#pragma unroll
            for (int k = 0; k < 8; ++k) vb[k] = Vs[mm][tx*8+k];
#pragma unroll
            for (int i = 0; i < 4; ++i)
#pragma unroll
                for (int k = 0; k < 8; ++k) o[i][k] += pa[i]*vb[k];
        }
    }
#pragma unroll
    for (int i = 0; i < 4; ++i) {
        float inv = 1.f / rsum[i];
        float* dst = O + ((size_t)bf*NN + n0 + ty*4 + i)*CCH + tx*8;
#pragma unroll
        for (int k = 0; k < 8; ++k) dst[k] = o[i][k]*inv;
    }
}

// ---------------- K6: yb[b][row][ci_oct16][xp196][8ci] (bf16) = x + shuffle(O) ----------------
__global__ __launch_bounds__(256) void k_shuffle_add(const float* __restrict__ O, const float* __restrict__ x,
                                                     uint4* __restrict__ yb) {
    __shared__ float t[128][65];
    int x0 = blockIdx.x * 64;
    int yy = blockIdx.y;
    int b  = blockIdx.z;
    int i = yy >> 3, dy = yy & 7;
#pragma unroll
    for (int k = 0; k < 32; ++k) {
        int idx = threadIdx.x + 256*k;
        int c = idx & 127, xl = idx >> 7;
        int xx = x0 + xl;
        int j = xx >> 3, dx = xx & 7;
        int bf = (b << 6) + (dy << 3) + dx;
        int n = i*SH + j;
        t[c][xl] = O[((size_t)bf*NN + n)*CCH + c];
    }
    __syncthreads();
    size_t base = (size_t)b*CHW + (size_t)yy*WW + x0;
#pragma unroll
    for (int k = 0; k < 32; ++k) {
        int idx = threadIdx.x + 256*k;
        int c = idx >> 6, xl = idx & 63;
        t[c][xl] += x[base + (size_t)c*HW + xl];
    }
    __syncthreads();
#pragma unroll
    for (int k = 0; k < 4; ++k) {
        int idx = threadIdx.x + 256*k;
        int xl = idx & 63, oc = idx >> 6;    // oc 0..15 (ci octet)
        uint32 d[4];
#pragma unroll
        for (int j = 0; j < 4; ++j) {
            float f0 = t[oc*8 + 2*j][xl];
            float f1 = t[oc*8 + 2*j + 1][xl];
            d[j] = (uint32)bf16r(f0) | ((uint32)bf16r(f1) << 16);
        }
        uint4 v; v.x = d[0]; v.y = d[1]; v.z = d[2]; v.w = d[3];
        yb[((size_t)(b*192 + yy)*16 + oc)*196 + (x0 + xl + 2)] = v;
    }
}

// ---------------- weight cast: w[co][ci][3][3] fp32 -> wb[tap][chunk][oct][co][8ci] bf16 ----------------
__global__ __launch_bounds__(256) void k_cast_w(const float* __restrict__ w1, const float* __restrict__ w2,
                                                uint4* __restrict__ wb1, uint4* __restrict__ wb2) {
    int id = blockIdx.x*256 + threadIdx.x;       // 0..18431
    const float* w = (blockIdx.y == 0) ? w1 : w2;
    uint4* wb = (blockIdx.y == 0) ? wb1 : wb2;
    int co = id & 127;
    int oct = (id >> 7) & 3;
    int chunk = (id >> 9) & 3;
    int tap = id >> 11;                           // 0..8
    int ci0 = chunk*32 + oct*8;
    uint32 r[4];
#pragma unroll
    for (int j = 0; j < 4; ++j) {
        float f0 = w[(size_t)(co*128 + ci0 + 2*j)*9 + tap];
        float f1 = w[(size_t)(co*128 + ci0 + 2*j + 1)*9 + tap];
        r[j] = (uint32)bf16r(f0) | ((uint32)bf16r(f1) << 16);
    }
    uint4 v; v.x = r[0]; v.y = r[1]; v.z = r[2]; v.w = r[3];
    wb[((size_t)(tap*4 + chunk)*4 + oct)*128 + co] = v;
}

// ---------------- K7/K8: 3x3 dilated conv as bf16 MFMA implicit GEMM ----------------
// Block: 4 waves; wave = 1 output row x 32 px x 128 co. Rows same parity: y0+{0,2,4,6}.
// K = 4 ci-chunks(32) x 9 taps; per tap: 16 x mfma_f32_16x16x32_bf16 per wave.
// mode 0: out bf16 padded NHWC-oct (+relu), mode 1: out fp32 NHWC (+relu).
__global__ __launch_bounds__(256, 3) void k_conv3m(const uint4* __restrict__ yb, const uint4* __restrict__ wb,
                                                   const float* __restrict__ bias, void* __restrict__ outp,
                                                   int mode) {
    __shared__ uint4 As[864];          // [r6][oct4][px36] 16B units
    __shared__ uint4 Ws[2][512];       // [oct4][co128]
    int xt = blockIdx.x;               // 0..5
    int rg = blockIdx.y;               // 0..47
    int b  = blockIdx.z;
    int par = rg & 1, g = rg >> 1;
    int y0 = 8*g + par;
    int x0 = xt*32;
    int tid = threadIdx.x;
    int wv = tid >> 6, l = tid & 63, quad = l >> 4, l15 = l & 15;
    int yw = y0 + 2*wv;

    floatx4 acc[2][8];
#pragma unroll
    for (int mt = 0; mt < 2; ++mt)
#pragma unroll
        for (int nt = 0; nt < 8; ++nt) acc[mt][nt] = (floatx4){0.f,0.f,0.f,0.f};

    const uint4* ybb = yb + (size_t)b*602112;   // 192*16*196

    for (int chunk = 0; chunk < 4; ++chunk) {
        __syncthreads();
        // stage A: 6 rows x 4 octs x 36 px
#pragma unroll
        for (int k = 0; k < 4; ++k) {
            int idx = tid + 256*k;
            if (idx < 864) {
                int r = idx / 144;
                int rem = idx - r*144;
                int oct = rem / 36;
                int px = rem - oct*36;
                int grow = y0 - 2 + 2*r;
                uint4 v; v.x = 0; v.y = 0; v.z = 0; v.w = 0;
                if (grow >= 0 && grow < 192)
                    v = ybb[((size_t)grow*16 + chunk*4 + oct)*196 + x0 + px];
                As[idx] = v;
            }
        }
        {   // stage weights tap 0 -> buf 0
            const uint4* src = wb + (size_t)chunk*512;
            Ws[0][tid]     = src[tid];
            Ws[0][tid+256] = src[tid+256];
        }
        __syncthreads();
#pragma unroll
        for (int tap = 0; tap < 9; ++tap) {
            if (tap < 8) {
                const uint4* src = wb + (size_t)((tap+1)*4 + chunk)*512;
                Ws[(tap+1)&1][tid]     = src[tid];
                Ws[(tap+1)&1][tid+256] = src[tid+256];
            }
            const int ky = tap/3, kx = tap - 3*(tap/3);
            int r = wv + ky;
            const short8 a0 = *(const short8*)&As[(r*4 + quad)*36 + l15 + 2*kx];
            const short8 a1 = *(const short8*)&As[(r*4 + quad)*36 + 16 + l15 + 2*kx];
            const uint4* wbuf = &Ws[tap&1][0];
#pragma unroll
            for (int nt = 0; nt < 8; ++nt) {
                const short8 bf = *(const short8*)&wbuf[quad*128 + nt*16 + l15];
                acc[0][nt] = __builtin_amdgcn_mfma_f32_16x16x32_bf16(a0, bf, acc[0][nt], 0, 0, 0);
                acc[1][nt] = __builtin_amdgcn_mfma_f32_16x16x32_bf16(a1, bf, acc[1][nt], 0, 0, 0);
            }
            __syncthreads();
        }
    }

    if (mode == 0) {
        unsigned short* outb = (unsigned short*)outp;
#pragma unroll
        for (int nt = 0; nt < 8; ++nt) {
            int co = nt*16 + l15;
            float bv = bias[co];
            size_t base = (((size_t)(b*192 + yw)*16 + ((co>>5)*4 + ((co>>3)&3)))*196)*8 + (size_t)(co&7);
#pragma unroll
            for (int mt = 0; mt < 2; ++mt)
#pragma unroll
                for (int rr = 0; rr < 4; ++rr) {
                    int xx = x0 + mt*16 + quad*4 + rr;
                    float v = fmaxf(acc[mt][nt][rr] + bv, 0.f);
                    outb[base + (size_t)(xx+2)*8] = bf16r(v);
                }
        }
    } else {
        float* outf = (float*)outp;
#pragma unroll
        for (int nt = 0; nt < 8; ++nt) {
            int co = nt*16 + l15;
            float bv = bias[co];
#pragma unroll
            for (int mt = 0; mt < 2; ++mt)
#pragma unroll
                for (int rr = 0; rr < 4; ++rr) {
                    int xx = x0 + mt*16 + quad*4 + rr;
                    float v = fmaxf(acc[mt][nt][rr] + bv, 0.f);
                    outf[((size_t)b*36864 + (size_t)yw*192 + xx)*128 + co] = v;
                }
        }
    }
}

// ---------------- K9: out = x + (w3 @ h) + b3  (1x1 conv), h in fp32 NHWC ----------------
__global__ __launch_bounds__(256) void k_conv1x1(const float* __restrict__ h, const float* __restrict__ w3,
                                                 const float* __restrict__ b3, const float* __restrict__ x,
                                                 float* __restrict__ out) {
    __shared__ float t[128][65];
    int pix0 = blockIdx.x * 64;
    int b = blockIdx.y;
    int tid = threadIdx.x;
#pragma unroll
    for (int k = 0; k < 32; ++k) {
        int idx = tid + 256*k;
        int ci = idx & 127, p = idx >> 7;
        t[ci][p] = h[((size_t)(b*36864 + pix0 + p))*128 + ci];
    }
    __syncthreads();
    int lane = tid & 63;
    int wave = __builtin_amdgcn_readfirstlane(tid >> 6);
    float acc[32];
#pragma unroll
    for (int k = 0; k < 32; ++k) acc[k] = 0.f;
    const float* wp = w3 + (size_t)wave*32*128;
    for (int ci = 0; ci < 128; ++ci) {
        float v = t[ci][lane];
#pragma unroll
        for (int k = 0; k < 32; ++k) acc[k] += wp[k*128 + ci] * v;
    }
#pragma unroll
    for (int k = 0; k < 32; ++k) {
        int co = wave*32 + k;
        size_t a = ((size_t)b*128 + co)*HW + pix0 + lane;
        out[a] = x[a] + acc[k] + b3[co];
    }
}

extern "C" void kernel_launch(void* const* d_in, const int* in_sizes, int n_in,
                              void* d_out, int out_size, void* d_ws, size_t ws_size,
                              hipStream_t stream) {
    (void)in_sizes; (void)n_in; (void)out_size; (void)ws_size;
    const float* x   = (const float*)d_in[0];
    const float* wqk = (const float*)d_in[1];
    const float* w1  = (const float*)d_in[2];
    const float* b1  = (const float*)d_in[3];
    const float* w2  = (const float*)d_in[4];
    const float* b2  = (const float*)d_in[5];
    const float* w3  = (const float*)d_in[6];
    const float* b3  = (const float*)d_in[7];
    float* out = (float*)d_out;
    char* ws = (char*)d_ws;
    float* stats = (float*)ws;
    const size_t SZ = (size_t)BF * NN * CCH * sizeof(float);   // 37,748,736 B
    const size_t YBSZ = (size_t)2*192*16*196*16;               // 19,267,584 B
    float* A  = (float*)(ws + 256);                            // V -> h1b(bf16) region
    float* Bb = (float*)(ws + 256 + SZ);                       // Xn -> O -> h2 fp32 NHWC
    float* Cc = (float*)(ws + 256 + 2*SZ);                     // qkn -> yb(bf16)
    uint4* yb  = (uint4*)Cc;
    uint4* h1b = (uint4*)A;
    uint4* wb1 = (uint4*)(ws + 256 + 20*1024*1024);            // in A region tail (free during convs)
    uint4* wb2 = (uint4*)(ws + 256 + 21*1024*1024);

    hipMemsetAsync(stats, 0, 4*sizeof(float), stream);
    k_reduce     <<<dim3(288, 2),     256, 0, stream>>>(x, stats);
    k_finalize   <<<1, 64,            0, stream>>>(stats);
    k_unshuffle  <<<dim3(3, 192, 2),  256, 0, stream>>>(x, stats, A, Bb);     // V->A, Xn->Bb
    k_qk         <<<1152,             256, 0, stream>>>(Bb, wqk, Cc);         // qkn->Cc
    k_attn       <<<dim3(9, 128),     256, 0, stream>>>(Cc, A, Bb);           // O->Bb
    // A and Cc are free now (V, qkn consumed)
    hipMemsetAsync(yb,  0, YBSZ, stream);                                     // yb pads
    hipMemsetAsync(h1b, 0, YBSZ, stream);                                     // h1b pads
    k_cast_w     <<<dim3(72, 2),      256, 0, stream>>>(w1, w2, wb1, wb2);
    k_shuffle_add<<<dim3(3, 192, 2),  256, 0, stream>>>(Bb, x, yb);           // yb = bf16(x+attn)
    k_conv3m     <<<dim3(6, 48, 2),   256, 0, stream>>>(yb,  wb1, b1, (void*)h1b, 0);  // h1 bf16 pad
    k_conv3m     <<<dim3(6, 48, 2),   256, 0, stream>>>(h1b, wb2, b2, (void*)Bb, 1);   // h2 fp32 NHWC
    k_conv1x1    <<<dim3(576, 2),     256, 0, stream>>>(Bb, w3, b3, x, out);  // out = x + conv1x1
}

// Round 4
// 514.711 us; speedup vs baseline: 7.1932x; 1.6311x over previous
//
#include <hip/hip_runtime.h>
#include <math.h>

#define CCH 128
#define HH 192
#define WW 192
#define BB 2
#define HW (HH*WW)        // 36864
#define CHW (CCH*HW)      // 4718592
#define BF 128            // B * f*f = 2*64
#define NN 576            // 24*24
#define SH 24

typedef __attribute__((ext_vector_type(8))) short short8;
typedef __attribute__((ext_vector_type(4))) float floatx4;
typedef unsigned int uint32;
typedef unsigned short ushort;

__device__ __forceinline__ unsigned short bf16r(float f) {
    uint32 u = __float_as_uint(f);
    u += 0x7fffu + ((u >> 16) & 1u);
    return (unsigned short)(u >> 16);
}

// ---------------- K1: per-batch sum / sumsq reduction ----------------
__global__ __launch_bounds__(256) void k_reduce(const float* __restrict__ x, float* __restrict__ stats) {
    int b = blockIdx.y;
    const float4* p = (const float4*)(x + (size_t)b*CHW) + (size_t)blockIdx.x*4096;
    float s = 0.f, sq = 0.f;
#pragma unroll
    for (int k = 0; k < 16; ++k) {
        float4 v = p[threadIdx.x + 256*k];
        s  += v.x + v.y + v.z + v.w;
        sq += v.x*v.x + v.y*v.y + v.z*v.z + v.w*v.w;
    }
    for (int off = 32; off; off >>= 1) { s += __shfl_down(s, off); sq += __shfl_down(sq, off); }
    __shared__ float ls[4], lq[4];
    int wave = threadIdx.x >> 6, lane = threadIdx.x & 63;
    if (lane == 0) { ls[wave] = s; lq[wave] = sq; }
    __syncthreads();
    if (threadIdx.x == 0) {
        atomicAdd(&stats[2*b],   ls[0]+ls[1]+ls[2]+ls[3]);
        atomicAdd(&stats[2*b+1], lq[0]+lq[1]+lq[2]+lq[3]);
    }
}

__global__ void k_finalize(float* stats) {
    int b = threadIdx.x;
    if (b < BB) {
        float s = stats[2*b], sq = stats[2*b+1];
        float mean = s / (float)CHW;
        float var = sq / (float)CHW - mean*mean;
        stats[4 + 2*b] = mean;
        stats[5 + 2*b] = rsqrtf(var + 1e-5f);
    }
}

// ---------------- K3: x -> V_t bf16 [Bf,C,N] and Xn fp32 [Bf,N,C] ----------------
__global__ __launch_bounds__(256) void k_unshuffle(const float* __restrict__ x, const float* __restrict__ stats,
                                                   ushort* __restrict__ Vt, float* __restrict__ Xn) {
    __shared__ float t[128][65];
    int x0 = blockIdx.x * 64;
    int y  = blockIdx.y;
    int b  = blockIdx.z;
    float mean = stats[4+2*b], istd = stats[5+2*b];
    const float* src = x + (size_t)b*CHW + (size_t)y*WW + x0;
#pragma unroll
    for (int k = 0; k < 32; ++k) {
        int idx = threadIdx.x + 256*k;
        int c = idx >> 6, xl = idx & 63;
        t[c][xl] = src[(size_t)c*HW + xl];
    }
    __syncthreads();
    int i = y >> 3, dy = y & 7;
#pragma unroll
    for (int k = 0; k < 32; ++k) {
        int idx = threadIdx.x + 256*k;
        int c = idx & 127, xl = idx >> 7;
        int xx = x0 + xl;
        int j = xx >> 3, dx = xx & 7;
        int bf = (b << 6) + (dy << 3) + dx;
        int n = i*SH + j;
        float v = t[c][xl];
        Vt[((size_t)bf*CCH + c)*NN + n] = bf16r(v);
        Xn[((size_t)bf*NN + n)*CCH + c] = (v - mean) * istd;
    }
}

// ---------------- K4: qkn(bf16) = normalize_rows(Xn @ wqk) ----------------
__global__ __launch_bounds__(256) void k_qk(const float* __restrict__ Xn, const float* __restrict__ wqk,
                                            ushort* __restrict__ qkn) {
    __shared__ float Qs[64][129];
    __shared__ float ssb[64][4];
    int bid = blockIdx.x;           // 0..1151
    int bf = bid / 9, tile = bid % 9;
    int n0 = tile * 64;
    const float* src = Xn + ((size_t)bf*NN + n0)*CCH;
#pragma unroll
    for (int k = 0; k < 32; ++k) {
        int idx = threadIdx.x + 256*k;
        Qs[idx >> 7][idx & 127] = src[idx];
    }
    __syncthreads();
    int lane = threadIdx.x & 63;
    int wave = __builtin_amdgcn_readfirstlane(threadIdx.x >> 6);
    float acc[32];
#pragma unroll
    for (int k = 0; k < 32; ++k) acc[k] = 0.f;
    const float* wp = wqk + wave*32;
    for (int c = 0; c < 128; ++c) {
        float qv = Qs[lane][c];
#pragma unroll
        for (int k = 0; k < 32; ++k) acc[k] += qv * wp[c*128 + k];
    }
    float ss = 0.f;
#pragma unroll
    for (int k = 0; k < 32; ++k) ss += acc[k]*acc[k];
    ssb[lane][wave] = ss;
    __syncthreads();
    float tot = ssb[lane][0]+ssb[lane][1]+ssb[lane][2]+ssb[lane][3];
    float f = 1.f / (sqrtf(tot) + 1e-8f);
    ushort* dst = qkn + ((size_t)bf*NN + n0 + lane)*CCH + wave*32;
#pragma unroll
    for (int g = 0; g < 4; ++g) {
        uint4 v;
        uint32 d[4];
#pragma unroll
        for (int j = 0; j < 4; ++j) {
            float f0 = acc[g*8 + 2*j] * f;
            float f1 = acc[g*8 + 2*j + 1] * f;
            d[j] = (uint32)bf16r(f0) | ((uint32)bf16r(f1) << 16);
        }
        v.x = d[0]; v.y = d[1]; v.z = d[2]; v.w = d[3];
        ((uint4*)dst)[g] = v;
    }
}

// ---------------- K5: MFMA flash attention  O[bf,n,c] fp32 ----------------
// Block: 64-query tile x C=128; 4 waves x 16 query rows. Chunks of 64 keys.
// S = Q K^T via 16x16x32 bf16 mfma (gemm_bt pattern: K rows are B^T rows).
// exp in C-layout regs (scores in [0.088,0.177] -> no max), P->LDS bf16 (same-wave
// round-trip, no barrier), rowsum via xor-shuffle over low-4 lane bits,
// PV with B^T = V^T rows from the pre-transposed V_t.
__global__ __launch_bounds__(256, 2) void k_attn(const ushort* __restrict__ qkn, const ushort* __restrict__ Vt_g,
                                                 float* __restrict__ O) {
    __shared__ ushort Qs[64*136];
    __shared__ ushort Ks[64*136];
    __shared__ ushort Vs[128*72];
    __shared__ ushort Ps[64*72];
    int tile = blockIdx.x, bf = blockIdx.y;
    int n0 = tile*64;
    int tid = threadIdx.x;
    int wv = tid >> 6, l = tid & 63, quad = l >> 4, l15 = l & 15;
    int qb = wv*16;

    // stage Q tile (64 x 128 bf16)
    {
        const uint4* qsrc = (const uint4*)(qkn + ((size_t)bf*NN + n0)*CCH);
#pragma unroll
        for (int k = 0; k < 4; ++k) {
            int idx = tid + 256*k;
            int row = idx >> 4, co = idx & 15;
            *(uint4*)&Qs[row*136 + co*8] = qsrc[idx];
        }
    }

    floatx4 oacc[8];
#pragma unroll
    for (int ct = 0; ct < 8; ++ct) oacc[ct] = (floatx4){0.f,0.f,0.f,0.f};
    float rsum[4] = {0.f,0.f,0.f,0.f};
    const float scale = 0.08838834764831845f;   // 1/sqrt(128)

    for (int mt = 0; mt < 9; ++mt) {
        int m0 = mt*64;
        __syncthreads();
        {
            const uint4* ksrc = (const uint4*)(qkn + ((size_t)bf*NN + m0)*CCH);
#pragma unroll
            for (int k = 0; k < 4; ++k) {
                int idx = tid + 256*k;
                int row = idx >> 4, co = idx & 15;
                *(uint4*)&Ks[row*136 + co*8] = ksrc[idx];
            }
            const uint4* vsrc = (const uint4*)(Vt_g + (size_t)bf*CCH*NN);   // [c][n], n-contig
            int mo8 = m0 >> 3;
#pragma unroll
            for (int k = 0; k < 4; ++k) {
                int idx = tid + 256*k;
                int c = idx >> 3, ko = idx & 7;
                *(uint4*)&Vs[c*72 + ko*8] = vsrc[(size_t)c*72 + mo8 + ko];
            }
        }
        __syncthreads();

        // S = Q K^T : 4 key-tiles, K-dim 128 = 4 mfma steps
        short8 aq[4];
#pragma unroll
        for (int kk = 0; kk < 4; ++kk)
            aq[kk] = *(const short8*)&Qs[(qb + l15)*136 + kk*32 + quad*8];
        floatx4 sc[4];
#pragma unroll
        for (int t = 0; t < 4; ++t) sc[t] = (floatx4){0.f,0.f,0.f,0.f};
#pragma unroll
        for (int kk = 0; kk < 4; ++kk)
#pragma unroll
            for (int t = 0; t < 4; ++t) {
                const short8 bk = *(const short8*)&Ks[(t*16 + l15)*136 + kk*32 + quad*8];
                sc[t] = __builtin_amdgcn_mfma_f32_16x16x32_bf16(aq[kk], bk, sc[t], 0, 0, 0);
            }

        // exp + P->LDS(bf16) + row-sums
        float pr[4] = {0.f,0.f,0.f,0.f};
#pragma unroll
        for (int t = 0; t < 4; ++t)
#pragma unroll
            for (int r = 0; r < 4; ++r) {
                float p = __expf((sc[t][r] + 1.f)*scale);
                Ps[(qb + quad*4 + r)*72 + t*16 + l15] = bf16r(p);
                pr[r] += p;
            }
#pragma unroll
        for (int off = 1; off < 16; off <<= 1)
#pragma unroll
            for (int r = 0; r < 4; ++r) pr[r] += __shfl_xor(pr[r], off);
#pragma unroll
        for (int r = 0; r < 4; ++r) rsum[r] += pr[r];

        // O += P V : 8 c-tiles, K-dim 64 keys = 2 mfma steps
        short8 ap[2];
        ap[0] = *(const short8*)&Ps[(qb + l15)*72 + quad*8];
        ap[1] = *(const short8*)&Ps[(qb + l15)*72 + 32 + quad*8];
#pragma unroll
        for (int ct = 0; ct < 8; ++ct)
#pragma unroll
            for (int kk2 = 0; kk2 < 2; ++kk2) {
                const short8 bv = *(const short8*)&Vs[(ct*16 + l15)*72 + kk2*32 + quad*8];
                oacc[ct] = __builtin_amdgcn_mfma_f32_16x16x32_bf16(ap[kk2], bv, oacc[ct], 0, 0, 0);
            }
    }

    float rinv[4];
#pragma unroll
    for (int r = 0; r < 4; ++r) rinv[r] = 1.f / rsum[r];
#pragma unroll
    for (int ct = 0; ct < 8; ++ct)
#pragma unroll
        for (int r = 0; r < 4; ++r)
            O[((size_t)bf*NN + n0 + qb + quad*4 + r)*CCH + ct*16 + l15] = oacc[ct][r]*rinv[r];
}

// ---------------- K6: yb[b][row][ci_oct16][xp196][8ci] (bf16) = x + shuffle(O) ----------------
__global__ __launch_bounds__(256) void k_shuffle_add(const float* __restrict__ O, const float* __restrict__ x,
                                                     uint4* __restrict__ yb) {
    __shared__ float t[128][65];
    int x0 = blockIdx.x * 64;
    int yy = blockIdx.y;
    int b  = blockIdx.z;
    int i = yy >> 3, dy = yy & 7;
#pragma unroll
    for (int k = 0; k < 32; ++k) {
        int idx = threadIdx.x + 256*k;
        int c = idx & 127, xl = idx >> 7;
        int xx = x0 + xl;
        int j = xx >> 3, dx = xx & 7;
        int bf = (b << 6) + (dy << 3) + dx;
        int n = i*SH + j;
        t[c][xl] = O[((size_t)bf*NN + n)*CCH + c];
    }
    __syncthreads();
    size_t base = (size_t)b*CHW + (size_t)yy*WW + x0;
#pragma unroll
    for (int k = 0; k < 32; ++k) {
        int idx = threadIdx.x + 256*k;
        int c = idx >> 6, xl = idx & 63;
        t[c][xl] += x[base + (size_t)c*HW + xl];
    }
    __syncthreads();
#pragma unroll
    for (int k = 0; k < 4; ++k) {
        int idx = threadIdx.x + 256*k;
        int xl = idx & 63, oc = idx >> 6;    // oc 0..15 (ci octet)
        uint32 d[4];
#pragma unroll
        for (int j = 0; j < 4; ++j) {
            float f0 = t[oc*8 + 2*j][xl];
            float f1 = t[oc*8 + 2*j + 1][xl];
            d[j] = (uint32)bf16r(f0) | ((uint32)bf16r(f1) << 16);
        }
        uint4 v; v.x = d[0]; v.y = d[1]; v.z = d[2]; v.w = d[3];
        yb[((size_t)(b*192 + yy)*16 + oc)*196 + (x0 + xl + 2)] = v;
    }
}

// ---------------- weight cast: w[co][ci][3][3] fp32 -> wb[tap][chunk][oct][co][8ci] bf16 ----------------
__global__ __launch_bounds__(256) void k_cast_w(const float* __restrict__ w1, const float* __restrict__ w2,
                                                uint4* __restrict__ wb1, uint4* __restrict__ wb2) {
    int id = blockIdx.x*256 + threadIdx.x;       // 0..18431
    const float* w = (blockIdx.y == 0) ? w1 : w2;
    uint4* wb = (blockIdx.y == 0) ? wb1 : wb2;
    int co = id & 127;
    int oct = (id >> 7) & 3;
    int chunk = (id >> 9) & 3;
    int tap = id >> 11;                           // 0..8
    int ci0 = chunk*32 + oct*8;
    uint32 r[4];
#pragma unroll
    for (int j = 0; j < 4; ++j) {
        float f0 = w[(size_t)(co*128 + ci0 + 2*j)*9 + tap];
        float f1 = w[(size_t)(co*128 + ci0 + 2*j + 1)*9 + tap];
        r[j] = (uint32)bf16r(f0) | ((uint32)bf16r(f1) << 16);
    }
    uint4 v; v.x = r[0]; v.y = r[1]; v.z = r[2]; v.w = r[3];
    wb[((size_t)(tap*4 + chunk)*4 + oct)*128 + co] = v;
}

// ---------------- K7/K8: 3x3 dilated conv as bf16 MFMA implicit GEMM ----------------
__global__ __launch_bounds__(256, 3) void k_conv3m(const uint4* __restrict__ yb, const uint4* __restrict__ wb,
                                                   const float* __restrict__ bias, void* __restrict__ outp,
                                                   int mode) {
    __shared__ uint4 As[864];          // [r6][oct4][px36] 16B units
    __shared__ uint4 Ws[2][512];       // [oct4][co128]
    int xt = blockIdx.x;               // 0..5
    int rg = blockIdx.y;               // 0..47
    int b  = blockIdx.z;
    int par = rg & 1, g = rg >> 1;
    int y0 = 8*g + par;
    int x0 = xt*32;
    int tid = threadIdx.x;
    int wv = tid >> 6, l = tid & 63, quad = l >> 4, l15 = l & 15;
    int yw = y0 + 2*wv;

    floatx4 acc[2][8];
#pragma unroll
    for (int mt = 0; mt < 2; ++mt)
#pragma unroll
        for (int nt = 0; nt < 8; ++nt) acc[mt][nt] = (floatx4){0.f,0.f,0.f,0.f};

    const uint4* ybb = yb + (size_t)b*602112;   // 192*16*196

    for (int chunk = 0; chunk < 4; ++chunk) {
        __syncthreads();
#pragma unroll
        for (int k = 0; k < 4; ++k) {
            int idx = tid + 256*k;
            if (idx < 864) {
                int r = idx / 144;
                int rem = idx - r*144;
                int oct = rem / 36;
                int px = rem - oct*36;
                int grow = y0 - 2 + 2*r;
                uint4 v; v.x = 0; v.y = 0; v.z = 0; v.w = 0;
                if (grow >= 0 && grow < 192)
                    v = ybb[((size_t)grow*16 + chunk*4 + oct)*196 + x0 + px];
                As[idx] = v;
            }
        }
        {
            const uint4* src = wb + (size_t)chunk*512;
            Ws[0][tid]     = src[tid];
            Ws[0][tid+256] = src[tid+256];
        }
        __syncthreads();
#pragma unroll
        for (int tap = 0; tap < 9; ++tap) {
            if (tap < 8) {
                const uint4* src = wb + (size_t)((tap+1)*4 + chunk)*512;
                Ws[(tap+1)&1][tid]     = src[tid];
                Ws[(tap+1)&1][tid+256] = src[tid+256];
            }
            const int ky = tap/3, kx = tap - 3*(tap/3);
            int r = wv + ky;
            const short8 a0 = *(const short8*)&As[(r*4 + quad)*36 + l15 + 2*kx];
            const short8 a1 = *(const short8*)&As[(r*4 + quad)*36 + 16 + l15 + 2*kx];
            const uint4* wbuf = &Ws[tap&1][0];
#pragma unroll
            for (int nt = 0; nt < 8; ++nt) {
                const short8 bf = *(const short8*)&wbuf[quad*128 + nt*16 + l15];
                acc[0][nt] = __builtin_amdgcn_mfma_f32_16x16x32_bf16(a0, bf, acc[0][nt], 0, 0, 0);
                acc[1][nt] = __builtin_amdgcn_mfma_f32_16x16x32_bf16(a1, bf, acc[1][nt], 0, 0, 0);
            }
            __syncthreads();
        }
    }

    if (mode == 0) {
        unsigned short* outb = (unsigned short*)outp;
#pragma unroll
        for (int nt = 0; nt < 8; ++nt) {
            int co = nt*16 + l15;
            float bv = bias[co];
            size_t base = (((size_t)(b*192 + yw)*16 + ((co>>5)*4 + ((co>>3)&3)))*196)*8 + (size_t)(co&7);
#pragma unroll
            for (int mt = 0; mt < 2; ++mt)
#pragma unroll
                for (int rr = 0; rr < 4; ++rr) {
                    int xx = x0 + mt*16 + quad*4 + rr;
                    float v = fmaxf(acc[mt][nt][rr] + bv, 0.f);
                    outb[base + (size_t)(xx+2)*8] = bf16r(v);
                }
        }
    } else {
        float* outf = (float*)outp;
#pragma unroll
        for (int nt = 0; nt < 8; ++nt) {
            int co = nt*16 + l15;
            float bv = bias[co];
#pragma unroll
            for (int mt = 0; mt < 2; ++mt)
#pragma unroll
                for (int rr = 0; rr < 4; ++rr) {
                    int xx = x0 + mt*16 + quad*4 + rr;
                    float v = fmaxf(acc[mt][nt][rr] + bv, 0.f);
                    outf[((size_t)b*36864 + (size_t)yw*192 + xx)*128 + co] = v;
                }
        }
    }
}

// ---------------- K9: out = x + (w3 @ h) + b3  (1x1 conv), h in fp32 NHWC ----------------
__global__ __launch_bounds__(256) void k_conv1x1(const float* __restrict__ h, const float* __restrict__ w3,
                                                 const float* __restrict__ b3, const float* __restrict__ x,
                                                 float* __restrict__ out) {
    __shared__ float t[128][65];
    int pix0 = blockIdx.x * 64;
    int b = blockIdx.y;
    int tid = threadIdx.x;
#pragma unroll
    for (int k = 0; k < 32; ++k) {
        int idx = tid + 256*k;
        int ci = idx & 127, p = idx >> 7;
        t[ci][p] = h[((size_t)(b*36864 + pix0 + p))*128 + ci];
    }
    __syncthreads();
    int lane = tid & 63;
    int wave = __builtin_amdgcn_readfirstlane(tid >> 6);
    float acc[32];
#pragma unroll
    for (int k = 0; k < 32; ++k) acc[k] = 0.f;
    const float* wp = w3 + (size_t)wave*32*128;
    for (int ci = 0; ci < 128; ++ci) {
        float v = t[ci][lane];
#pragma unroll
        for (int k = 0; k < 32; ++k) acc[k] += wp[k*128 + ci] * v;
    }
#pragma unroll
    for (int k = 0; k < 32; ++k) {
        int co = wave*32 + k;
        size_t a = ((size_t)b*128 + co)*HW + pix0 + lane;
        out[a] = x[a] + acc[k] + b3[co];
    }
}

extern "C" void kernel_launch(void* const* d_in, const int* in_sizes, int n_in,
                              void* d_out, int out_size, void* d_ws, size_t ws_size,
                              hipStream_t stream) {
    (void)in_sizes; (void)n_in; (void)out_size; (void)ws_size;
    const float* x   = (const float*)d_in[0];
    const float* wqk = (const float*)d_in[1];
    const float* w1  = (const float*)d_in[2];
    const float* b1  = (const float*)d_in[3];
    const float* w2  = (const float*)d_in[4];
    const float* b2  = (const float*)d_in[5];
    const float* w3  = (const float*)d_in[6];
    const float* b3  = (const float*)d_in[7];
    float* out = (float*)d_out;
    char* ws = (char*)d_ws;
    float* stats = (float*)ws;
    const size_t SZ = (size_t)BF * NN * CCH * sizeof(float);   // 37,748,736 B
    const size_t YBSZ = (size_t)2*192*16*196*16;               // 19,267,584 B
    // region A (37.7MB): V_t bf16 (18.9MB) -> later h1b bf16 (19.27MB); wb1/wb2 at +20/21MB
    // region B (37.7MB): Xn fp32 -> O fp32 -> h2 fp32 NHWC
    // region C (37.7MB): qkn bf16 (18.9MB) -> later yb bf16 (19.27MB)
    char* Abase = ws + 256;
    char* Bbase = ws + 256 + SZ;
    char* Cbase = ws + 256 + 2*SZ;
    ushort* Vt  = (ushort*)Abase;
    float*  Xn  = (float*)Bbase;
    ushort* qkn = (ushort*)Cbase;
    float*  O   = (float*)Bbase;
    uint4*  yb  = (uint4*)Cbase;
    uint4*  h1b = (uint4*)Abase;
    float*  h2  = (float*)Bbase;
    uint4* wb1 = (uint4*)(Abase + 20*1024*1024);
    uint4* wb2 = (uint4*)(Abase + 21*1024*1024);

    hipMemsetAsync(stats, 0, 4*sizeof(float), stream);
    k_reduce     <<<dim3(288, 2),     256, 0, stream>>>(x, stats);
    k_finalize   <<<1, 64,            0, stream>>>(stats);
    k_unshuffle  <<<dim3(3, 192, 2),  256, 0, stream>>>(x, stats, Vt, Xn);
    k_qk         <<<1152,             256, 0, stream>>>(Xn, wqk, qkn);
    k_attn       <<<dim3(9, 128),     256, 0, stream>>>(qkn, Vt, O);
    hipMemsetAsync(yb,  0, YBSZ, stream);                      // yb pads (qkn consumed)
    hipMemsetAsync(h1b, 0, YBSZ, stream);                      // h1b pads (Vt consumed)
    k_cast_w     <<<dim3(72, 2),      256, 0, stream>>>(w1, w2, wb1, wb2);
    k_shuffle_add<<<dim3(3, 192, 2),  256, 0, stream>>>(O, x, yb);
    k_conv3m     <<<dim3(6, 48, 2),   256, 0, stream>>>(yb,  wb1, b1, (void*)h1b, 0);
    k_conv3m     <<<dim3(6, 48, 2),   256, 0, stream>>>(h1b, wb2, b2, (void*)h2, 1);
    k_conv1x1    <<<dim3(576, 2),     256, 0, stream>>>(h2, w3, b3, x, out);
}

// Round 5
// 412.609 us; speedup vs baseline: 8.9732x; 1.2475x over previous
//
#include <hip/hip_runtime.h>
#include <math.h>

#define CCH 128
#define HH 192
#define WW 192
#define BB 2
#define HW (HH*WW)        // 36864
#define CHW (CCH*HW)      // 4718592
#define BF 128            // B * f*f = 2*64
#define NN 576            // 24*24
#define SH 24

typedef __attribute__((ext_vector_type(8))) short short8;
typedef __attribute__((ext_vector_type(4))) float floatx4;
typedef unsigned int uint32;
typedef unsigned short ushort;

__device__ __forceinline__ unsigned short bf16r(float f) {
    uint32 u = __float_as_uint(f);
    u += 0x7fffu + ((u >> 16) & 1u);
    return (unsigned short)(u >> 16);
}

// ---------------- K1: per-batch sum / sumsq reduction ----------------
__global__ __launch_bounds__(256) void k_reduce(const float* __restrict__ x, float* __restrict__ stats) {
    int b = blockIdx.y;
    const float4* p = (const float4*)(x + (size_t)b*CHW) + (size_t)blockIdx.x*4096;
    float s = 0.f, sq = 0.f;
#pragma unroll
    for (int k = 0; k < 16; ++k) {
        float4 v = p[threadIdx.x + 256*k];
        s  += v.x + v.y + v.z + v.w;
        sq += v.x*v.x + v.y*v.y + v.z*v.z + v.w*v.w;
    }
    for (int off = 32; off; off >>= 1) { s += __shfl_down(s, off); sq += __shfl_down(sq, off); }
    __shared__ float ls[4], lq[4];
    int wave = threadIdx.x >> 6, lane = threadIdx.x & 63;
    if (lane == 0) { ls[wave] = s; lq[wave] = sq; }
    __syncthreads();
    if (threadIdx.x == 0) {
        atomicAdd(&stats[2*b],   ls[0]+ls[1]+ls[2]+ls[3]);
        atomicAdd(&stats[2*b+1], lq[0]+lq[1]+lq[2]+lq[3]);
    }
}

__global__ void k_finalize(float* stats) {
    int b = threadIdx.x;
    if (b < BB) {
        float s = stats[2*b], sq = stats[2*b+1];
        float mean = s / (float)CHW;
        float var = sq / (float)CHW - mean*mean;
        stats[4 + 2*b] = mean;
        stats[5 + 2*b] = rsqrtf(var + 1e-5f);
    }
}

// ---------------- K3: x -> V_t bf16 [Bf,C,N] and Xn fp32 [Bf,N,C] ----------------
__global__ __launch_bounds__(256) void k_unshuffle(const float* __restrict__ x, const float* __restrict__ stats,
                                                   ushort* __restrict__ Vt, float* __restrict__ Xn) {
    __shared__ float t[128][65];
    int x0 = blockIdx.x * 64;
    int y  = blockIdx.y;
    int b  = blockIdx.z;
    float mean = stats[4+2*b], istd = stats[5+2*b];
    const float* src = x + (size_t)b*CHW + (size_t)y*WW + x0;
#pragma unroll
    for (int k = 0; k < 32; ++k) {
        int idx = threadIdx.x + 256*k;
        int c = idx >> 6, xl = idx & 63;
        t[c][xl] = src[(size_t)c*HW + xl];
    }
    __syncthreads();
    int i = y >> 3, dy = y & 7;
#pragma unroll
    for (int k = 0; k < 32; ++k) {
        int idx = threadIdx.x + 256*k;
        int c = idx & 127, xl = idx >> 7;
        int xx = x0 + xl;
        int j = xx >> 3, dx = xx & 7;
        int bf = (b << 6) + (dy << 3) + dx;
        int n = i*SH + j;
        float v = t[c][xl];
        Vt[((size_t)bf*CCH + c)*NN + n] = bf16r(v);
        Xn[((size_t)bf*NN + n)*CCH + c] = (v - mean) * istd;
    }
}

// ---------------- K4: qkn(bf16) = normalize_rows(Xn @ wqk) ----------------
__global__ __launch_bounds__(256) void k_qk(const float* __restrict__ Xn, const float* __restrict__ wqk,
                                            ushort* __restrict__ qkn) {
    __shared__ float Qs[64][129];
    __shared__ float ssb[64][4];
    int bid = blockIdx.x;           // 0..1151
    int bf = bid / 9, tile = bid % 9;
    int n0 = tile * 64;
    const float* src = Xn + ((size_t)bf*NN + n0)*CCH;
#pragma unroll
    for (int k = 0; k < 32; ++k) {
        int idx = threadIdx.x + 256*k;
        Qs[idx >> 7][idx & 127] = src[idx];
    }
    __syncthreads();
    int lane = threadIdx.x & 63;
    int wave = __builtin_amdgcn_readfirstlane(threadIdx.x >> 6);
    float acc[32];
#pragma unroll
    for (int k = 0; k < 32; ++k) acc[k] = 0.f;
    const float* wp = wqk + wave*32;
    for (int c = 0; c < 128; ++c) {
        float qv = Qs[lane][c];
#pragma unroll
        for (int k = 0; k < 32; ++k) acc[k] += qv * wp[c*128 + k];
    }
    float ss = 0.f;
#pragma unroll
    for (int k = 0; k < 32; ++k) ss += acc[k]*acc[k];
    ssb[lane][wave] = ss;
    __syncthreads();
    float tot = ssb[lane][0]+ssb[lane][1]+ssb[lane][2]+ssb[lane][3];
    float f = 1.f / (sqrtf(tot) + 1e-8f);
    ushort* dst = qkn + ((size_t)bf*NN + n0 + lane)*CCH + wave*32;
#pragma unroll
    for (int g = 0; g < 4; ++g) {
        uint4 v;
        uint32 d[4];
#pragma unroll
        for (int j = 0; j < 4; ++j) {
            float f0 = acc[g*8 + 2*j] * f;
            float f1 = acc[g*8 + 2*j + 1] * f;
            d[j] = (uint32)bf16r(f0) | ((uint32)bf16r(f1) << 16);
        }
        v.x = d[0]; v.y = d[1]; v.z = d[2]; v.w = d[3];
        ((uint4*)dst)[g] = v;
    }
}

// ---------------- K5: MFMA flash attention  O[bf,n,c] fp32 ----------------
__global__ __launch_bounds__(256, 2) void k_attn(const ushort* __restrict__ qkn, const ushort* __restrict__ Vt_g,
                                                 float* __restrict__ O) {
    __shared__ ushort Qs[64*136];
    __shared__ ushort Ks[64*136];
    __shared__ ushort Vs[128*72];
    __shared__ ushort Ps[64*72];
    int tile = blockIdx.x, bf = blockIdx.y;
    int n0 = tile*64;
    int tid = threadIdx.x;
    int wv = tid >> 6, l = tid & 63, quad = l >> 4, l15 = l & 15;
    int qb = wv*16;

    {
        const uint4* qsrc = (const uint4*)(qkn + ((size_t)bf*NN + n0)*CCH);
#pragma unroll
        for (int k = 0; k < 4; ++k) {
            int idx = tid + 256*k;
            int row = idx >> 4, co = idx & 15;
            *(uint4*)&Qs[row*136 + co*8] = qsrc[idx];
        }
    }

    floatx4 oacc[8];
#pragma unroll
    for (int ct = 0; ct < 8; ++ct) oacc[ct] = (floatx4){0.f,0.f,0.f,0.f};
    float rsum[4] = {0.f,0.f,0.f,0.f};
    const float scale = 0.08838834764831845f;   // 1/sqrt(128)

    for (int mt = 0; mt < 9; ++mt) {
        int m0 = mt*64;
        __syncthreads();
        {
            const uint4* ksrc = (const uint4*)(qkn + ((size_t)bf*NN + m0)*CCH);
#pragma unroll
            for (int k = 0; k < 4; ++k) {
                int idx = tid + 256*k;
                int row = idx >> 4, co = idx & 15;
                *(uint4*)&Ks[row*136 + co*8] = ksrc[idx];
            }
            const uint4* vsrc = (const uint4*)(Vt_g + (size_t)bf*CCH*NN);   // [c][n], n-contig
            int mo8 = m0 >> 3;
#pragma unroll
            for (int k = 0; k < 4; ++k) {
                int idx = tid + 256*k;
                int c = idx >> 3, ko = idx & 7;
                *(uint4*)&Vs[c*72 + ko*8] = vsrc[(size_t)c*72 + mo8 + ko];
            }
        }
        __syncthreads();

        short8 aq[4];
#pragma unroll
        for (int kk = 0; kk < 4; ++kk)
            aq[kk] = *(const short8*)&Qs[(qb + l15)*136 + kk*32 + quad*8];
        floatx4 sc[4];
#pragma unroll
        for (int t = 0; t < 4; ++t) sc[t] = (floatx4){0.f,0.f,0.f,0.f};
#pragma unroll
        for (int kk = 0; kk < 4; ++kk)
#pragma unroll
            for (int t = 0; t < 4; ++t) {
                const short8 bk = *(const short8*)&Ks[(t*16 + l15)*136 + kk*32 + quad*8];
                sc[t] = __builtin_amdgcn_mfma_f32_16x16x32_bf16(aq[kk], bk, sc[t], 0, 0, 0);
            }

        float pr[4] = {0.f,0.f,0.f,0.f};
#pragma unroll
        for (int t = 0; t < 4; ++t)
#pragma unroll
            for (int r = 0; r < 4; ++r) {
                float p = __expf((sc[t][r] + 1.f)*scale);
                Ps[(qb + quad*4 + r)*72 + t*16 + l15] = bf16r(p);
                pr[r] += p;
            }
#pragma unroll
        for (int off = 1; off < 16; off <<= 1)
#pragma unroll
            for (int r = 0; r < 4; ++r) pr[r] += __shfl_xor(pr[r], off);
#pragma unroll
        for (int r = 0; r < 4; ++r) rsum[r] += pr[r];

        short8 ap[2];
        ap[0] = *(const short8*)&Ps[(qb + l15)*72 + quad*8];
        ap[1] = *(const short8*)&Ps[(qb + l15)*72 + 32 + quad*8];
#pragma unroll
        for (int ct = 0; ct < 8; ++ct)
#pragma unroll
            for (int kk2 = 0; kk2 < 2; ++kk2) {
                const short8 bv = *(const short8*)&Vs[(ct*16 + l15)*72 + kk2*32 + quad*8];
                oacc[ct] = __builtin_amdgcn_mfma_f32_16x16x32_bf16(ap[kk2], bv, oacc[ct], 0, 0, 0);
            }
    }

    float rinv[4];
#pragma unroll
    for (int r = 0; r < 4; ++r) rinv[r] = 1.f / rsum[r];
#pragma unroll
    for (int ct = 0; ct < 8; ++ct)
#pragma unroll
        for (int r = 0; r < 4; ++r)
            O[((size_t)bf*NN + n0 + qb + quad*4 + r)*CCH + ct*16 + l15] = oacc[ct][r]*rinv[r];
}

// ---------------- K6: yb[b][row][ci_oct16][xp196][8ci] (bf16) = x + shuffle(O) ----------------
__global__ __launch_bounds__(256) void k_shuffle_add(const float* __restrict__ O, const float* __restrict__ x,
                                                     uint4* __restrict__ yb) {
    __shared__ float t[128][65];
    int x0 = blockIdx.x * 64;
    int yy = blockIdx.y;
    int b  = blockIdx.z;
    int i = yy >> 3, dy = yy & 7;
#pragma unroll
    for (int k = 0; k < 32; ++k) {
        int idx = threadIdx.x + 256*k;
        int c = idx & 127, xl = idx >> 7;
        int xx = x0 + xl;
        int j = xx >> 3, dx = xx & 7;
        int bf = (b << 6) + (dy << 3) + dx;
        int n = i*SH + j;
        t[c][xl] = O[((size_t)bf*NN + n)*CCH + c];
    }
    __syncthreads();
    size_t base = (size_t)b*CHW + (size_t)yy*WW + x0;
#pragma unroll
    for (int k = 0; k < 32; ++k) {
        int idx = threadIdx.x + 256*k;
        int c = idx >> 6, xl = idx & 63;
        t[c][xl] += x[base + (size_t)c*HW + xl];
    }
    __syncthreads();
#pragma unroll
    for (int k = 0; k < 4; ++k) {
        int idx = threadIdx.x + 256*k;
        int xl = idx & 63, oc = idx >> 6;    // oc 0..15 (ci octet)
        uint32 d[4];
#pragma unroll
        for (int j = 0; j < 4; ++j) {
            float f0 = t[oc*8 + 2*j][xl];
            float f1 = t[oc*8 + 2*j + 1][xl];
            d[j] = (uint32)bf16r(f0) | ((uint32)bf16r(f1) << 16);
        }
        uint4 v; v.x = d[0]; v.y = d[1]; v.z = d[2]; v.w = d[3];
        yb[((size_t)(b*192 + yy)*16 + oc)*196 + (x0 + xl + 2)] = v;
    }
}

// ---------------- weight casts ----------------
// y=0/1: w1/w2 -> wb[tap][chunk][oct][co][8ci] bf16;  y=2: w3 -> w3b[co][ci] bf16
__global__ __launch_bounds__(256) void k_cast_w(const float* __restrict__ w1, const float* __restrict__ w2,
                                                const float* __restrict__ w3,
                                                uint4* __restrict__ wb1, uint4* __restrict__ wb2,
                                                uint4* __restrict__ w3b) {
    int id = blockIdx.x*256 + threadIdx.x;       // 0..18431
    if (blockIdx.y == 2) {
        if (id < 2048) {
            int co = id >> 4, oct = id & 15;
            uint32 r[4];
#pragma unroll
            for (int j = 0; j < 4; ++j) {
                float f0 = w3[(size_t)co*128 + oct*8 + 2*j];
                float f1 = w3[(size_t)co*128 + oct*8 + 2*j + 1];
                r[j] = (uint32)bf16r(f0) | ((uint32)bf16r(f1) << 16);
            }
            uint4 v; v.x = r[0]; v.y = r[1]; v.z = r[2]; v.w = r[3];
            w3b[id] = v;
        }
        return;
    }
    const float* w = (blockIdx.y == 0) ? w1 : w2;
    uint4* wb = (blockIdx.y == 0) ? wb1 : wb2;
    int co = id & 127;
    int oct = (id >> 7) & 3;
    int chunk = (id >> 9) & 3;
    int tap = id >> 11;                           // 0..8
    int ci0 = chunk*32 + oct*8;
    uint32 r[4];
#pragma unroll
    for (int j = 0; j < 4; ++j) {
        float f0 = w[(size_t)(co*128 + ci0 + 2*j)*9 + tap];
        float f1 = w[(size_t)(co*128 + ci0 + 2*j + 1)*9 + tap];
        r[j] = (uint32)bf16r(f0) | ((uint32)bf16r(f1) << 16);
    }
    uint4 v; v.x = r[0]; v.y = r[1]; v.z = r[2]; v.w = r[3];
    wb[((size_t)(tap*4 + chunk)*4 + oct)*128 + co] = v;
}

// ---------------- K7/K8: 3x3 dilated conv as bf16 MFMA implicit GEMM ----------------
// mode 0: out bf16 padded NHWC-oct (+relu); mode 1: out bf16 flat NHWC [b][px][128] (+relu)
__global__ __launch_bounds__(256, 3) void k_conv3m(const uint4* __restrict__ yb, const uint4* __restrict__ wb,
                                                   const float* __restrict__ bias, void* __restrict__ outp,
                                                   int mode) {
    __shared__ uint4 As[864];          // [r6][oct4][px36] 16B units
    __shared__ uint4 Ws[2][512];       // [oct4][co128]
    int xt = blockIdx.x;               // 0..5
    int rg = blockIdx.y;               // 0..47
    int b  = blockIdx.z;
    int par = rg & 1, g = rg >> 1;
    int y0 = 8*g + par;
    int x0 = xt*32;
    int tid = threadIdx.x;
    int wv = tid >> 6, l = tid & 63, quad = l >> 4, l15 = l & 15;
    int yw = y0 + 2*wv;

    floatx4 acc[2][8];
#pragma unroll
    for (int mt = 0; mt < 2; ++mt)
#pragma unroll
        for (int nt = 0; nt < 8; ++nt) acc[mt][nt] = (floatx4){0.f,0.f,0.f,0.f};

    const uint4* ybb = yb + (size_t)b*602112;   // 192*16*196

    for (int chunk = 0; chunk < 4; ++chunk) {
        __syncthreads();
#pragma unroll
        for (int k = 0; k < 4; ++k) {
            int idx = tid + 256*k;
            if (idx < 864) {
                int r = idx / 144;
                int rem = idx - r*144;
                int oct = rem / 36;
                int px = rem - oct*36;
                int grow = y0 - 2 + 2*r;
                uint4 v; v.x = 0; v.y = 0; v.z = 0; v.w = 0;
                if (grow >= 0 && grow < 192)
                    v = ybb[((size_t)grow*16 + chunk*4 + oct)*196 + x0 + px];
                As[idx] = v;
            }
        }
        {
            const uint4* src = wb + (size_t)chunk*512;
            Ws[0][tid]     = src[tid];
            Ws[0][tid+256] = src[tid+256];
        }
        __syncthreads();
#pragma unroll
        for (int tap = 0; tap < 9; ++tap) {
            if (tap < 8) {
                const uint4* src = wb + (size_t)((tap+1)*4 + chunk)*512;
                Ws[(tap+1)&1][tid]     = src[tid];
                Ws[(tap+1)&1][tid+256] = src[tid+256];
            }
            const int ky = tap/3, kx = tap - 3*(tap/3);
            int r = wv + ky;
            const short8 a0 = *(const short8*)&As[(r*4 + quad)*36 + l15 + 2*kx];
            const short8 a1 = *(const short8*)&As[(r*4 + quad)*36 + 16 + l15 + 2*kx];
            const uint4* wbuf = &Ws[tap&1][0];
#pragma unroll
            for (int nt = 0; nt < 8; ++nt) {
                const short8 bf = *(const short8*)&wbuf[quad*128 + nt*16 + l15];
                acc[0][nt] = __builtin_amdgcn_mfma_f32_16x16x32_bf16(a0, bf, acc[0][nt], 0, 0, 0);
                acc[1][nt] = __builtin_amdgcn_mfma_f32_16x16x32_bf16(a1, bf, acc[1][nt], 0, 0, 0);
            }
            __syncthreads();
        }
    }

    if (mode == 0) {
        unsigned short* outb = (unsigned short*)outp;
#pragma unroll
        for (int nt = 0; nt < 8; ++nt) {
            int co = nt*16 + l15;
            float bv = bias[co];
            size_t base = (((size_t)(b*192 + yw)*16 + ((co>>5)*4 + ((co>>3)&3)))*196)*8 + (size_t)(co&7);
#pragma unroll
            for (int mt = 0; mt < 2; ++mt)
#pragma unroll
                for (int rr = 0; rr < 4; ++rr) {
                    int xx = x0 + mt*16 + quad*4 + rr;
                    float v = fmaxf(acc[mt][nt][rr] + bv, 0.f);
                    outb[base + (size_t)(xx+2)*8] = bf16r(v);
                }
        }
    } else {
        unsigned short* outb = (unsigned short*)outp;   // flat NHWC bf16 [b][px][128]
#pragma unroll
        for (int nt = 0; nt < 8; ++nt) {
            int co = nt*16 + l15;
            float bv = bias[co];
#pragma unroll
            for (int mt = 0; mt < 2; ++mt)
#pragma unroll
                for (int rr = 0; rr < 4; ++rr) {
                    int xx = x0 + mt*16 + quad*4 + rr;
                    float v = fmaxf(acc[mt][nt][rr] + bv, 0.f);
                    outb[((size_t)b*36864 + (size_t)yw*192 + xx)*128 + co] = bf16r(v);
                }
        }
    }
}

// ---------------- K9: out = x + (w3 @ h2b) + b3 via MFMA, h2b bf16 NHWC ----------------
// Block: 128 px x 128 co, 4 waves (wave = 32 px). Stage h-tile + w3 in LDS (136-stride pad).
__global__ __launch_bounds__(256, 2) void k_conv1x1m(const ushort* __restrict__ h2b, const uint4* __restrict__ w3b,
                                                     const float* __restrict__ b3, const float* __restrict__ x,
                                                     float* __restrict__ out) {
    __shared__ ushort Hs[128*136];
    __shared__ ushort Ws3[128*136];
    int px0 = blockIdx.x * 128;
    int b = blockIdx.y;
    int tid = threadIdx.x;
    int wv = tid >> 6, l = tid & 63, quad = l >> 4, l15 = l & 15;

    {
        const uint4* hsrc = (const uint4*)(h2b + ((size_t)b*36864 + px0)*128);
#pragma unroll
        for (int k = 0; k < 8; ++k) {
            int idx = tid + 256*k;
            int row = idx >> 4, co8 = idx & 15;
            *(uint4*)&Hs[row*136 + co8*8] = hsrc[idx];
            *(uint4*)&Ws3[row*136 + co8*8] = w3b[idx];
        }
    }
    __syncthreads();

    floatx4 oacc[2][8];
#pragma unroll
    for (int mt = 0; mt < 2; ++mt)
#pragma unroll
        for (int nt = 0; nt < 8; ++nt) oacc[mt][nt] = (floatx4){0.f,0.f,0.f,0.f};

#pragma unroll
    for (int kk = 0; kk < 4; ++kk) {
        const short8 aq0 = *(const short8*)&Hs[(wv*32 + l15)*136 + kk*32 + quad*8];
        const short8 aq1 = *(const short8*)&Hs[(wv*32 + 16 + l15)*136 + kk*32 + quad*8];
#pragma unroll
        for (int nt = 0; nt < 8; ++nt) {
            const short8 bw = *(const short8*)&Ws3[(nt*16 + l15)*136 + kk*32 + quad*8];
            oacc[0][nt] = __builtin_amdgcn_mfma_f32_16x16x32_bf16(aq0, bw, oacc[0][nt], 0, 0, 0);
            oacc[1][nt] = __builtin_amdgcn_mfma_f32_16x16x32_bf16(aq1, bw, oacc[1][nt], 0, 0, 0);
        }
    }

#pragma unroll
    for (int nt = 0; nt < 8; ++nt) {
        int co = nt*16 + l15;
        float bv = b3[co];
        size_t pbase = ((size_t)b*128 + co)*HW + px0 + wv*32 + quad*4;
#pragma unroll
        for (int mt = 0; mt < 2; ++mt) {
            const float4 xv = *(const float4*)&x[pbase + mt*16];
            float4 o;
            o.x = oacc[mt][nt][0] + bv + xv.x;
            o.y = oacc[mt][nt][1] + bv + xv.y;
            o.z = oacc[mt][nt][2] + bv + xv.z;
            o.w = oacc[mt][nt][3] + bv + xv.w;
            *(float4*)&out[pbase + mt*16] = o;
        }
    }
}

extern "C" void kernel_launch(void* const* d_in, const int* in_sizes, int n_in,
                              void* d_out, int out_size, void* d_ws, size_t ws_size,
                              hipStream_t stream) {
    (void)in_sizes; (void)n_in; (void)out_size; (void)ws_size;
    const float* x   = (const float*)d_in[0];
    const float* wqk = (const float*)d_in[1];
    const float* w1  = (const float*)d_in[2];
    const float* b1  = (const float*)d_in[3];
    const float* w2  = (const float*)d_in[4];
    const float* b2  = (const float*)d_in[5];
    const float* w3  = (const float*)d_in[6];
    const float* b3  = (const float*)d_in[7];
    float* out = (float*)d_out;
    char* ws = (char*)d_ws;
    float* stats = (float*)ws;
    const size_t SZ = (size_t)BF * NN * CCH * sizeof(float);   // 37,748,736 B
    const size_t YBSZ = (size_t)2*192*16*196*16;               // 19,267,584 B
    char* Abase = ws + 256;
    char* Bbase = ws + 256 + SZ;
    char* Cbase = ws + 256 + 2*SZ;
    ushort* Vt  = (ushort*)Abase;
    float*  Xn  = (float*)Bbase;
    ushort* qkn = (ushort*)Cbase;
    float*  O   = (float*)Bbase;
    uint4*  yb  = (uint4*)Cbase;
    uint4*  h1b = (uint4*)Abase;
    ushort* h2b = (ushort*)Bbase;      // bf16 NHWC flat, 18.9 MB
    uint4* wb1 = (uint4*)(Abase + 20*1024*1024);
    uint4* wb2 = (uint4*)(Abase + 21*1024*1024);
    uint4* w3b = (uint4*)(Abase + 22*1024*1024);

    hipMemsetAsync(stats, 0, 4*sizeof(float), stream);
    k_reduce     <<<dim3(288, 2),     256, 0, stream>>>(x, stats);
    k_finalize   <<<1, 64,            0, stream>>>(stats);
    k_unshuffle  <<<dim3(3, 192, 2),  256, 0, stream>>>(x, stats, Vt, Xn);
    k_qk         <<<1152,             256, 0, stream>>>(Xn, wqk, qkn);
    k_attn       <<<dim3(9, 128),     256, 0, stream>>>(qkn, Vt, O);
    hipMemsetAsync(yb,  0, YBSZ, stream);
    hipMemsetAsync(h1b, 0, YBSZ, stream);
    k_cast_w     <<<dim3(72, 3),      256, 0, stream>>>(w1, w2, w3, wb1, wb2, w3b);
    k_shuffle_add<<<dim3(3, 192, 2),  256, 0, stream>>>(O, x, yb);
    k_conv3m     <<<dim3(6, 48, 2),   256, 0, stream>>>(yb,  wb1, b1, (void*)h1b, 0);
    k_conv3m     <<<dim3(6, 48, 2),   256, 0, stream>>>(h1b, wb2, b2, (void*)h2b, 1);
    k_conv1x1m   <<<dim3(288, 2),     256, 0, stream>>>(h2b, w3b, b3, x, out);
}